// Round 8
// baseline (282.834 us; speedup 1.0000x reference)
//
#include <hip/hip_runtime.h>
#include <stdint.h>

typedef _Float16 f16;
typedef _Float16 f16x8 __attribute__((ext_vector_type(8)));
typedef float floatx4 __attribute__((ext_vector_type(4)));
typedef unsigned short u16;

#define PDIM 16

__device__ __forceinline__ floatx4 mfma_16x16x32(f16x8 a, f16x8 b, floatx4 c) {
  return __builtin_amdgcn_mfma_f32_16x16x32_f16(a, b, c, 0, 0, 0);
}

// async 16B/lane global->LDS; LDS dst = wave-uniform base + lane*16.
__device__ __forceinline__ void stage16(const f16* g, f16* lds_base) {
  __builtin_amdgcn_global_load_lds(
      (const __attribute__((address_space(1))) void*)g,
      (__attribute__((address_space(3))) void*)lds_base, 16, 0, 0);
}

// raw barrier + fine-grained vmcnt (hipBLASLt-style pipeline control).
// 3 DMAs per wave per K-tile (2xA + 1xB) -> steady-state wait = vmcnt(3).
#define WAITVM3() asm volatile("s_waitcnt vmcnt(3)" ::: "memory")
#define WAITVM0() asm volatile("s_waitcnt vmcnt(0)" ::: "memory")
#define BAR()     asm volatile("s_barrier" ::: "memory")
// Fence: pin register-only MFMAs (+their lgkm waits) inside the iteration so
// no ds_read of buf[(it-1)%3] is still pending when the next iteration's DMA
// overwrites it (rule #18: "memory" clobber does not order MFMA).
#define SCHEDFENCE() __builtin_amdgcn_sched_barrier(0)
// R6 lessons kept: no setprio (lockstep-null), no Nc cap (h0 already L3-hot).
// R7 lesson: 128x128/4-wave structure is sync-bound at ~105us/GEMM (654 TF ==
// 2-phase ceiling). This version: 256x128 tile, 8 waves -> 2x MFMA per sync,
// half the barrier events, same verified vmcnt/barrier/fence discipline.

// XCD-affinity block swizzle (T1): used ONLY in kgemm2 (A = h0[p] is per-p).
__device__ __forceinline__ void decode_block(int b, int nwg, int& p, int& ht,
                                             int& nt) {
  const int NT = nwg >> 6;  // number of 256-row n-tiles
  if ((NT & 7) == 0) {
    const int x  = b & 7;        // XCD id under round-robin dispatch
    const int u  = b >> 3;       // sequence within XCD, [0, 8*NT)
    const int cg = u >> 6;       // nt-group index, [0, NT/8)
    const int i  = u & 63;       // 8 ntl x 2 pl x 4 ht
    ht = i & 3;
    const int pl  = (i >> 2) & 1;
    const int ntl = i >> 3;
    p  = x * 2 + pl;
    nt = cg * 8 + ntl;
  } else {
    p  = b & 15;
    ht = (b >> 4) & 3;
    nt = b >> 6;
  }
}

// LDS granule swizzle (T2 adapted for global_load_lds, rule #21):
//   LDS write stays linear; global source pre-swizzled (kch); read applies
//   the same involution (qs). Bit-identical arithmetic vs unswizzled.

// ---- fused prep ----
// [0,2048): W0/W1 transpose, register-only: lane owns output row h; 16
//   coalesced scalar fp32 reads W[e][h]; 2x uint4 f16 stores WT[h][e..e+15].
// [2048,2048+nConvBlk): emb fp32->f16. Then biases+W2 pack (fp32).
__global__ __launch_bounds__(256) void kprep(const float* __restrict__ emb,
                                             const float* __restrict__ W0,
                                             const float* __restrict__ W1,
                                             const float* __restrict__ b0,
                                             const float* __restrict__ b1,
                                             const float* __restrict__ W2,
                                             const float* __restrict__ b2,
                                             f16* __restrict__ embB,
                                             f16* __restrict__ W0T,
                                             f16* __restrict__ W1T,
                                             float* __restrict__ smallF,
                                             int n8, int nConvBlk) {
  const int b = blockIdx.x;
  const int t = threadIdx.x;
  if (b < 2048) {
    const int m  = b >> 10;
    const int p  = (b >> 6) & 15;
    const int tr = (b >> 3) & 7;   // e-tile (64 e)
    const int tc = b & 7;          // h-tile (64 h)
    const float* src = (m ? W1 : W0) + ((size_t)p << 18);
    f16*         dst = (m ? W1T : W0T) + ((size_t)p << 18);
    const int w = t >> 6;          // wave: e-subrange [w*16, w*16+16)
    const int l = t & 63;          // lane: h offset
    const int h  = tc * 64 + l;
    const int e0 = tr * 64 + w * 16;
    const float* sp = src + (size_t)e0 * 512 + h;
    float v[16];
#pragma unroll
    for (int j = 0; j < 16; ++j) v[j] = sp[(size_t)j * 512];
    union { f16 hh[16]; uint4 u[2]; } o;
#pragma unroll
    for (int j = 0; j < 16; ++j) o.hh[j] = (f16)v[j];
    f16* dp = dst + (size_t)h * 512 + e0;
    ((uint4*)dp)[0] = o.u[0];
    ((uint4*)dp)[1] = o.u[1];
  } else if (b < 2048 + nConvBlk) {
    const int i = (b - 2048) * 256 + t;
    if (i < n8) {
      const float4* s = (const float4*)emb;
      float4 a = s[i * 2], bb = s[i * 2 + 1];
      union { f16 h[8]; uint4 v; } o;
      o.h[0] = (f16)a.x;  o.h[1] = (f16)a.y;  o.h[2] = (f16)a.z;  o.h[3] = (f16)a.w;
      o.h[4] = (f16)bb.x; o.h[5] = (f16)bb.y; o.h[6] = (f16)bb.z; o.h[7] = (f16)bb.w;
      *(uint4*)(embB + (size_t)i * 8) = o.v;
    }
  } else {
    const int j = (b - 2048 - nConvBlk) * 256 + t;
    if (j < 24592) {
      const float* src;
      int off;
      if (j < 8192)       { src = b0; off = j; }
      else if (j < 16384) { src = b1; off = j - 8192; }
      else if (j < 24576) { src = W2; off = j - 16384; }
      else                { src = b2; off = j - 24576; }
      smallF[j] = src[off];
    }
  }
}

// ---- layer 0: h0 = relu(emb . W0T^T + b0), fp16 out.
// 256x128 tile, 8 waves, BK=32, 16x16x32 MFMA 4x4 acc/wave; TRIPLE-buffered
// distance-2 staging, counted vmcnt(3), raw barrier, per-iter sched fence.
__global__ __launch_bounds__(512) void kgemm1(const f16* __restrict__ emb,
                                              const f16* __restrict__ W0T,
                                              const float* __restrict__ small,
                                              f16* __restrict__ h0,
                                              int Nc) {
  __shared__ f16 smem[36864];  // A: 3x8192 @0 | B: 3x4096 @24576; epi 64x136
  const int b  = blockIdx.x;
  const int p  = b & 15;
  const int ht = (b >> 4) & 3;
  const int nt = b >> 6;
  const int n0 = nt * 256;
  const int hc0 = ht * 128;
  const int tid = threadIdx.x;
  const int w = tid >> 6;          // 0..7
  const int lane = tid & 63;
  const int q = lane >> 4;
  const int mm = lane & 15;
  const int wr = (w >> 1) * 64;    // 0,64,128,192
  const int wc = (w & 1) * 64;     // 0,64
  const int srow = lane >> 2;
  const int kch  = (((lane & 3) ^ ((lane >> 3) & 3)) * 8);
  const int qs   = (q ^ ((mm >> 1) & 3)) * 8;

  const f16* Arow = emb + (size_t)n0 * 512;
  const f16* Brow = W0T + ((size_t)p << 18) + (size_t)hc0 * 512;

  floatx4 acc[4][4];
#pragma unroll
  for (int i = 0; i < 4; ++i)
#pragma unroll
    for (int j = 0; j < 4; ++j) acc[i][j] = floatx4{0.f, 0.f, 0.f, 0.f};

  const int r0 = w * 16 + srow;    // 0..127 (8 waves x 16 rows)
  // prologue: tiles 0,1 (3 DMAs per wave each: A rows r0, 128+r0; B rows r0)
#pragma unroll
  for (int tpre = 0; tpre < 2; ++tpre) {
    const int kn = tpre * 32;
    f16* Ab = smem + tpre * 8192;
    f16* Bb = smem + 24576 + tpre * 4096;
    stage16(Arow + (size_t)r0 * 512 + kn + kch, Ab + (w * 16) * 32);
    stage16(Arow + (size_t)(128 + r0) * 512 + kn + kch, Ab + (128 + w * 16) * 32);
    stage16(Brow + (size_t)r0 * 512 + kn + kch, Bb + (w * 16) * 32);
  }

#pragma unroll
  for (int it = 0; it < 16; ++it) {
    if (it < 15) { WAITVM3(); } else { WAITVM0(); }  // own tile-it landed
    BAR();  // all waves: tile-it landed; buf[(it+2)%3] no longer being read
    if (it + 2 < 16) {
      const int nb = (it + 2) % 3;
      const int kn = (it + 2) * 32;
      f16* Ab = smem + nb * 8192;
      f16* Bb = smem + 24576 + nb * 4096;
      stage16(Arow + (size_t)r0 * 512 + kn + kch, Ab + (w * 16) * 32);
      stage16(Arow + (size_t)(128 + r0) * 512 + kn + kch, Ab + (128 + w * 16) * 32);
      stage16(Brow + (size_t)r0 * 512 + kn + kch, Bb + (w * 16) * 32);
    }
    const int cb = it % 3;
    const f16* A = smem + cb * 8192;
    const f16* B = smem + 24576 + cb * 4096;
    f16x8 af[4], bv[4];
#pragma unroll
    for (int rt = 0; rt < 4; ++rt)
      af[rt] = *(const f16x8*)&A[(wr + rt * 16 + mm) * 32 + qs];
#pragma unroll
    for (int ct = 0; ct < 4; ++ct)
      bv[ct] = *(const f16x8*)&B[(wc + ct * 16 + mm) * 32 + qs];
#pragma unroll
    for (int rt = 0; rt < 4; ++rt)
#pragma unroll
      for (int ct = 0; ct < 4; ++ct)
        acc[rt][ct] = mfma_16x16x32(af[rt], bv[ct], acc[rt][ct]);
    SCHEDFENCE();  // pin MFMAs + lgkm waits before next iteration's barrier
  }
  SCHEDFENCE();

  // coalesced epilogue via LDS (stride 136), four 64-row passes
  __syncthreads();
  f16* Cst = smem;
#pragma unroll
  for (int pass = 0; pass < 4; ++pass) {
    if ((w >> 1) == pass) {
#pragma unroll
      for (int ct = 0; ct < 4; ++ct) {
        const float bvv = small[p * 512 + hc0 + wc + ct * 16 + mm];
#pragma unroll
        for (int rt = 0; rt < 4; ++rt)
#pragma unroll
          for (int r = 0; r < 4; ++r) {
            float v = acc[rt][ct][r] + bvv;
            v = v > 0.f ? v : 0.f;
            Cst[(rt * 16 + q * 4 + r) * 136 + wc + ct * 16 + mm] = (f16)v;
          }
      }
    }
    __syncthreads();
#pragma unroll
    for (int i = 0; i < 2; ++i) {
      const int row = (tid >> 4) + i * 32;   // 0..63
      const int chunk = tid & 15;
      uint4 v = *(const uint4*)&Cst[row * 136 + chunk * 8];
      *(uint4*)&h0[((size_t)p * Nc + n0 + pass * 64 + row) * 512 + hc0 +
                   chunk * 8] = v;
    }
    if (pass < 3) __syncthreads();
  }
}

// ---- layer 1 GEMM + fused partial layer-2 dot; same pipelined core ----
// XCD-affinity swizzle kept here (A = h0[p] is per-p).
__global__ __launch_bounds__(512) void kgemm2(const f16* __restrict__ h0,
                                              const f16* __restrict__ W1T,
                                              const float* __restrict__ small,
                                              float* __restrict__ pacc,
                                              int Nc) {
  __shared__ f16 smem[36864];
  __shared__ float oacc[256];
  int p, ht, nt;
  decode_block(blockIdx.x, gridDim.x, p, ht, nt);
  const int n0 = nt * 256;
  const int hc0 = ht * 128;
  const int tid = threadIdx.x;
  const int w = tid >> 6;
  const int lane = tid & 63;
  const int q = lane >> 4;
  const int mm = lane & 15;
  const int wr = (w >> 1) * 64;
  const int wc = (w & 1) * 64;
  const int srow = lane >> 2;
  const int kch = (((lane & 3) ^ ((lane >> 3) & 3)) * 8);
  const int qs  = (q ^ ((mm >> 1) & 3)) * 8;
  if (tid < 256) oacc[tid] = 0.f;

  const f16* Arow = h0 + ((size_t)p * Nc + n0) * 512;
  const f16* Brow = W1T + ((size_t)p << 18) + (size_t)hc0 * 512;

  floatx4 acc[4][4];
#pragma unroll
  for (int i = 0; i < 4; ++i)
#pragma unroll
    for (int j = 0; j < 4; ++j) acc[i][j] = floatx4{0.f, 0.f, 0.f, 0.f};

  const int r0 = w * 16 + srow;
#pragma unroll
  for (int tpre = 0; tpre < 2; ++tpre) {
    const int kn = tpre * 32;
    f16* Ab = smem + tpre * 8192;
    f16* Bb = smem + 24576 + tpre * 4096;
    stage16(Arow + (size_t)r0 * 512 + kn + kch, Ab + (w * 16) * 32);
    stage16(Arow + (size_t)(128 + r0) * 512 + kn + kch, Ab + (128 + w * 16) * 32);
    stage16(Brow + (size_t)r0 * 512 + kn + kch, Bb + (w * 16) * 32);
  }

#pragma unroll
  for (int it = 0; it < 16; ++it) {
    if (it < 15) { WAITVM3(); } else { WAITVM0(); }
    BAR();
    if (it + 2 < 16) {
      const int nb = (it + 2) % 3;
      const int kn = (it + 2) * 32;
      f16* Ab = smem + nb * 8192;
      f16* Bb = smem + 24576 + nb * 4096;
      stage16(Arow + (size_t)r0 * 512 + kn + kch, Ab + (w * 16) * 32);
      stage16(Arow + (size_t)(128 + r0) * 512 + kn + kch, Ab + (128 + w * 16) * 32);
      stage16(Brow + (size_t)r0 * 512 + kn + kch, Bb + (w * 16) * 32);
    }
    const int cb = it % 3;
    const f16* A = smem + cb * 8192;
    const f16* B = smem + 24576 + cb * 4096;
    f16x8 af[4], bv[4];
#pragma unroll
    for (int rt = 0; rt < 4; ++rt)
      af[rt] = *(const f16x8*)&A[(wr + rt * 16 + mm) * 32 + qs];
#pragma unroll
    for (int ct = 0; ct < 4; ++ct)
      bv[ct] = *(const f16x8*)&B[(wc + ct * 16 + mm) * 32 + qs];
#pragma unroll
    for (int rt = 0; rt < 4; ++rt)
#pragma unroll
      for (int ct = 0; ct < 4; ++ct)
        acc[rt][ct] = mfma_16x16x32(af[rt], bv[ct], acc[rt][ct]);
    SCHEDFENCE();  // pin MFMAs + lgkm waits before next iteration's barrier
  }
  SCHEDFENCE();

  // epilogue: h1 = relu(acc + b1); pd[row] += h1 * W2[col]
  float pd[4][4];
#pragma unroll
  for (int i = 0; i < 4; ++i)
#pragma unroll
    for (int r = 0; r < 4; ++r) pd[i][r] = 0.f;
#pragma unroll
  for (int ct = 0; ct < 4; ++ct) {
    const int col = hc0 + wc + ct * 16 + mm;
    const float b1v = small[8192 + p * 512 + col];
    const float w2v = small[16384 + p * 512 + col];
#pragma unroll
    for (int rt = 0; rt < 4; ++rt)
#pragma unroll
      for (int r = 0; r < 4; ++r) {
        float v = acc[rt][ct][r] + b1v;
        v = v > 0.f ? v : 0.f;
        pd[rt][r] += v * w2v;
      }
  }
#pragma unroll
  for (int rt = 0; rt < 4; ++rt)
#pragma unroll
    for (int r = 0; r < 4; ++r) {
      float v = pd[rt][r];
      v += __shfl_xor(v, 1, 16);
      v += __shfl_xor(v, 2, 16);
      v += __shfl_xor(v, 4, 16);
      v += __shfl_xor(v, 8, 16);
      if (mm == 0) atomicAdd(&oacc[wr + rt * 16 + q * 4 + r], v);
    }
  __syncthreads();
  if (tid < 256)
    pacc[(size_t)(p * 4 + ht) * Nc + n0 + tid] = oacc[tid];
}

// ---- finish: sum 4 ht partials + b2, sigmoid, fp32 out ----
__global__ __launch_bounds__(256) void kfin(const float* __restrict__ pacc,
                                            const float* __restrict__ small,
                                            float* __restrict__ out, int Nc) {
  const int idx = blockIdx.x * 256 + threadIdx.x;
  if (idx >= Nc * 16) return;
  const int n = idx >> 4;
  const int p = idx & 15;
  float v = small[24576 + p];
#pragma unroll
  for (int ht = 0; ht < 4; ++ht) v += pacc[(size_t)(p * 4 + ht) * Nc + n];
  out[(size_t)n * 16 + p] = 1.f / (1.f + expf(-v));
}

// ---- fallback (tiny ws / odd N): slow but correct, fp32 in/out ----
__global__ __launch_bounds__(64) void knaive(const float* __restrict__ emb,
                                             const float* __restrict__ W0,
                                             const float* __restrict__ b0,
                                             const float* __restrict__ W1,
                                             const float* __restrict__ b1,
                                             const float* __restrict__ W2,
                                             const float* __restrict__ b2,
                                             float* __restrict__ out) {
  const int n = blockIdx.x >> 4;
  const int p = blockIdx.x & 15;
  __shared__ float h0s[512];
  __shared__ float h1s[512];
  const size_t wb = (size_t)p << 18;
  const int t = threadIdx.x;
  for (int h = t; h < 512; h += 64) {
    float a = 0.f;
    for (int e = 0; e < 512; ++e)
      a += emb[(size_t)n * 512 + e] * W0[wb + (size_t)e * 512 + h];
    a += b0[p * 512 + h];
    h0s[h] = a > 0.f ? a : 0.f;
  }
  __syncthreads();
  for (int k = t; k < 512; k += 64) {
    float a = 0.f;
    for (int hh = 0; hh < 512; ++hh)
      a += h0s[hh] * W1[wb + (size_t)hh * 512 + k];
    a += b1[p * 512 + k];
    h1s[k] = a > 0.f ? a : 0.f;
  }
  __syncthreads();
  float s = 0.f;
  for (int k = t; k < 512; k += 64) s += h1s[k] * W2[p * 512 + k];
  for (int off = 32; off; off >>= 1) s += __shfl_down(s, off, 64);
  if (t == 0)
    out[(size_t)n * 16 + p] = 1.f / (1.f + expf(-(s + b2[p])));
}

extern "C" void kernel_launch(void* const* d_in, const int* in_sizes, int n_in,
                              void* d_out, int out_size, void* d_ws, size_t ws_size,
                              hipStream_t stream) {
  (void)n_in; (void)out_size;
  const float* emb = (const float*)d_in[0];
  const float* W0  = (const float*)d_in[1];
  const float* b0  = (const float*)d_in[2];
  const float* W1  = (const float*)d_in[3];
  const float* b1  = (const float*)d_in[4];
  const float* W2  = (const float*)d_in[5];
  const float* b2  = (const float*)d_in[6];
  float* out = (float*)d_out;

  const int N = in_sizes[0] / 512;

  char* ws = (char*)d_ws;
  f16*   W0T    = (f16*)ws;                                  // 8 MB
  f16*   W1T    = (f16*)(ws + (8ll << 20));                  // 8 MB
  float* smallF = (float*)(ws + (16ll << 20));               // 128 KB (96.1 used)
  float* pacc   = (float*)(ws + (16ll << 20) + 131072);      // 256*N B
  f16*   embB   = (f16*)(ws + (16ll << 20) + 131072 + (size_t)N * 256);
  f16*   h0     = (f16*)(ws + (16ll << 20) + 131072 + (size_t)N * 256 +
                         (size_t)N * 1024);
  const long long fixed = (16ll << 20) + 131072 + (long long)N * 256 +
                          (long long)N * 1024;
  long long avail = (long long)ws_size - fixed;
  long long rows = avail > 0 ? avail / (16 * 512 * 2) : 0;
  int Nc = (int)((rows / 256) * 256);   // 256-row tile granularity
  if (Nc > N) Nc = N;

  if (Nc < 256 || (N % 256) != 0) {
    knaive<<<dim3(N * PDIM), dim3(64), 0, stream>>>(emb, W0, b0, W1, b1, W2,
                                                    b2, out);
    return;
  }

  const int n8 = N * 512 / 8;
  const int nConvBlk = (n8 + 255) / 256;
  kprep<<<dim3(2048 + nConvBlk + 97), dim3(256), 0, stream>>>(
      emb, W0, W1, b0, b1, W2, b2, embB, W0T, W1T, smallF, n8, nConvBlk);

  for (int noff = 0; noff < N; noff += Nc) {
    const int cur = (N - noff < Nc) ? (N - noff) : Nc;
    kgemm1<<<dim3(64 * (cur / 256)), dim3(512), 0, stream>>>(
        embB + (size_t)noff * 512, W0T, smallF, h0, cur);
    kgemm2<<<dim3(64 * (cur / 256)), dim3(512), 0, stream>>>(
        h0, W1T, smallF, pacc, cur);
    kfin<<<dim3((cur * 16 + 255) / 256), dim3(256), 0, stream>>>(
        pacc, smallF, out + (size_t)noff * 16, cur);
  }
}

// Round 9
// 247.311 us; speedup vs baseline: 1.1436x; 1.1436x over previous
//
#include <hip/hip_runtime.h>
#include <stdint.h>

typedef _Float16 f16;
typedef _Float16 f16x8 __attribute__((ext_vector_type(8)));
typedef float floatx4 __attribute__((ext_vector_type(4)));
typedef unsigned short u16;

#define PDIM 16

__device__ __forceinline__ floatx4 mfma_16x16x32(f16x8 a, f16x8 b, floatx4 c) {
  return __builtin_amdgcn_mfma_f32_16x16x32_f16(a, b, c, 0, 0, 0);
}

// async 16B/lane global->LDS; LDS dst = wave-uniform base + lane*16.
__device__ __forceinline__ void stage16(const f16* g, f16* lds_base) {
  __builtin_amdgcn_global_load_lds(
      (const __attribute__((address_space(1))) void*)g,
      (__attribute__((address_space(3))) void*)lds_base, 16, 0, 0);
}

#define WAITVM4() asm volatile("s_waitcnt vmcnt(4)" ::: "memory")
#define WAITVM2() asm volatile("s_waitcnt vmcnt(2)" ::: "memory")
#define WAITVM0() asm volatile("s_waitcnt vmcnt(0)" ::: "memory")
#define BAR()     asm volatile("s_barrier" ::: "memory")
#define LGKM0()   asm volatile("s_waitcnt lgkmcnt(0)" ::: "memory")
#define SCHEDFENCE() __builtin_amdgcn_sched_barrier(0)
#define PRIO1() __builtin_amdgcn_s_setprio(1)
#define PRIO0() __builtin_amdgcn_s_setprio(0)

// ===================== 8-phase 256x256 GEMM core notes =====================
// R1-R8 established: the 2-barrier-per-K-step structure is pinned at ~105us
// (654 TF = the 2-phase ceiling) regardless of tile/waves/swizzle/setprio.
// This kernel ports the quadrant-phased schedule (m201-style) in plain HIP:
//  - BM=BN=256, BK=64, 8 waves (512 thr). Wave tile per quadrant: 32x64.
//  - acc[qm][qn][rt][ct]: 2x2 quadrants x (2x4) 16x16 frags = 128 VGPR.
//  - LDS: A/B each 2buf x 2half x [128][64] f16 = 128 KB total; granule
//    swizzle: logical (row, g) stored at slot g^(row&7) (conflict-free b128).
//  - Staging unit = one (matrix, half) 16 KB = 2 global_load_lds/thread.
//    Issue order per K-tile t+1 (at phases 0..3 of t): [A0, B0, B1, A1]
//    == first-use order of phase sequence [(qm,qn)] = [(0,0),(0,1),(1,1),(1,0)].
//  - Derived waits: vmcnt(4) at phases 0,1,2 (tail tile: 4/2/0), none at 3.
//    Loads stay in flight across barriers; never drained in steady state.
//  - Per phase: {vmcnt; barrier; ds_read (only the frags newly needed: 12/8/4/8);
//    issue 1 unit; lgkmcnt(0); setprio(1); 16 MFMA; setprio(0); sched fence}.
//  - K accumulation order identical to the 2-phase version (16 chunks of 32,
//    in order) -> h0 bit-identical.
// ==========================================================================

// XCD-affinity decode for kgemm2 (A = h0[p] is per-p; measured win).
__device__ __forceinline__ void decode_block2(int b, int nwg, int& p, int& ht,
                                              int& nt) {
  const int NT = nwg >> 5;  // number of 256-row n-tiles
  if ((NT & 7) == 0) {
    const int x  = b & 7;
    const int u  = b >> 3;
    const int i  = u & 31;     // 8 ntl x 2 pl x 2 ht
    const int cg = u >> 5;
    ht = i & 1;
    const int pl  = (i >> 1) & 1;
    const int ntl = i >> 2;
    p  = x * 2 + pl;
    nt = cg * 8 + ntl;
  } else {
    p  = b & 15;
    ht = (b >> 4) & 1;
    nt = b >> 5;
  }
}

// ---- fused prep: W0/W1 transpose (register-only, coalesced reads); emb
// fp32->f16; biases+W2 pack (fp32). ----
__global__ __launch_bounds__(256) void kprep(const float* __restrict__ emb,
                                             const float* __restrict__ W0,
                                             const float* __restrict__ W1,
                                             const float* __restrict__ b0,
                                             const float* __restrict__ b1,
                                             const float* __restrict__ W2,
                                             const float* __restrict__ b2,
                                             f16* __restrict__ embB,
                                             f16* __restrict__ W0T,
                                             f16* __restrict__ W1T,
                                             float* __restrict__ smallF,
                                             int n8, int nConvBlk) {
  const int b = blockIdx.x;
  const int t = threadIdx.x;
  if (b < 2048) {
    const int m  = b >> 10;
    const int p  = (b >> 6) & 15;
    const int tr = (b >> 3) & 7;
    const int tc = b & 7;
    const float* src = (m ? W1 : W0) + ((size_t)p << 18);
    f16*         dst = (m ? W1T : W0T) + ((size_t)p << 18);
    const int w = t >> 6;
    const int l = t & 63;
    const int h  = tc * 64 + l;
    const int e0 = tr * 64 + w * 16;
    const float* sp = src + (size_t)e0 * 512 + h;
    float v[16];
#pragma unroll
    for (int j = 0; j < 16; ++j) v[j] = sp[(size_t)j * 512];
    union { f16 hh[16]; uint4 u[2]; } o;
#pragma unroll
    for (int j = 0; j < 16; ++j) o.hh[j] = (f16)v[j];
    f16* dp = dst + (size_t)h * 512 + e0;
    ((uint4*)dp)[0] = o.u[0];
    ((uint4*)dp)[1] = o.u[1];
  } else if (b < 2048 + nConvBlk) {
    const int i = (b - 2048) * 256 + t;
    if (i < n8) {
      const float4* s = (const float4*)emb;
      float4 a = s[i * 2], bb = s[i * 2 + 1];
      union { f16 h[8]; uint4 v; } o;
      o.h[0] = (f16)a.x;  o.h[1] = (f16)a.y;  o.h[2] = (f16)a.z;  o.h[3] = (f16)a.w;
      o.h[4] = (f16)bb.x; o.h[5] = (f16)bb.y; o.h[6] = (f16)bb.z; o.h[7] = (f16)bb.w;
      *(uint4*)(embB + (size_t)i * 8) = o.v;
    }
  } else {
    const int j = (b - 2048 - nConvBlk) * 256 + t;
    if (j < 24592) {
      const float* src;
      int off;
      if (j < 8192)       { src = b0; off = j; }
      else if (j < 16384) { src = b1; off = j - 8192; }
      else if (j < 24576) { src = W2; off = j - 16384; }
      else                { src = b2; off = j - 24576; }
      smallF[j] = src[off];
    }
  }
}

// stage one (matrix, half) unit: 16 KB, 2 loads per thread, fixed order.
__device__ __forceinline__ void stageU(const f16* M, int h, int tt, f16* buf,
                                       int w, int srow8, int kg8) {
  stage16(M + (size_t)(h * 128 + w * 8 + srow8) * 512 + tt * 64 + kg8,
          buf + (w * 8) * 64);
  stage16(M + (size_t)(h * 128 + 64 + w * 8 + srow8) * 512 + tt * 64 + kg8,
          buf + (64 + w * 8) * 64);
}

// core K-loop shared by both GEMMs (macro-free explicit code in each kernel
// would be huge; use an inline func filling acc).
__device__ __forceinline__ void gemm_core(const f16* __restrict__ Arow,
                                          const f16* __restrict__ Brow,
                                          f16* smem, floatx4 (*acc)[2][2][4],
                                          int w, int lane) {
  const int q   = lane >> 4;
  const int mm  = lane & 15;
  const int mm7 = mm & 7;
  const int qwr = (w & 3) * 32;
  const int qwc = (w >> 2) * 64;
  const int srow8 = lane >> 3;
  const int kg8   = (((lane & 7) ^ ((lane >> 3) & 7)) * 8);

  // LDS layout: A halves at (buf*2+h)*8192; B halves at 32768 + (buf*2+h)*8192
  // prologue: tile 0 units in first-use order [A0, B0, B1, A1]
  stageU(Arow, 0, 0, smem + 0 * 8192, w, srow8, kg8);
  stageU(Brow, 0, 0, smem + 32768 + 0 * 8192, w, srow8, kg8);
  stageU(Brow, 1, 0, smem + 32768 + 1 * 8192, w, srow8, kg8);
  stageU(Arow, 1, 0, smem + 1 * 8192, w, srow8, kg8);

  f16x8 af[2][2], bv[4][2];

  for (int t = 0; t < 8; ++t) {
    const int cb = t & 1;
    const f16* Ah0 = smem + (cb * 2 + 0) * 8192;
    const f16* Ah1 = smem + (cb * 2 + 1) * 8192;
    const f16* Bh0 = smem + 32768 + (cb * 2 + 0) * 8192;
    const f16* Bh1 = smem + 32768 + (cb * 2 + 1) * 8192;
    const int nb = cb ^ 1;
    f16* nAh0 = smem + (nb * 2 + 0) * 8192;
    f16* nAh1 = smem + (nb * 2 + 1) * 8192;
    f16* nBh0 = smem + 32768 + (nb * 2 + 0) * 8192;
    f16* nBh1 = smem + 32768 + (nb * 2 + 1) * 8192;

    // ---- phase 0: quadrant (qm0, qn0) ----
    WAITVM4();
    BAR();
#pragma unroll
    for (int rt = 0; rt < 2; ++rt)
#pragma unroll
      for (int ks = 0; ks < 2; ++ks)
        af[rt][ks] = *(const f16x8*)&Ah0[(qwr + rt * 16 + mm) * 64 +
                                         (((ks * 4 + q) ^ mm7)) * 8];
#pragma unroll
    for (int ct = 0; ct < 4; ++ct)
#pragma unroll
      for (int ks = 0; ks < 2; ++ks)
        bv[ct][ks] = *(const f16x8*)&Bh0[(qwc + ct * 16 + mm) * 64 +
                                         (((ks * 4 + q) ^ mm7)) * 8];
    if (t < 7) stageU(Arow, 0, t + 1, nAh0, w, srow8, kg8);
    LGKM0();
    PRIO1();
#pragma unroll
    for (int rt = 0; rt < 2; ++rt)
#pragma unroll
      for (int ct = 0; ct < 4; ++ct)
#pragma unroll
        for (int ks = 0; ks < 2; ++ks)
          acc[0][0][rt][ct] = mfma_16x16x32(af[rt][ks], bv[ct][ks],
                                            acc[0][0][rt][ct]);
    PRIO0();
    SCHEDFENCE();

    // ---- phase 1: quadrant (qm0, qn1) — af held, read B half 1 ----
    if (t < 7) { WAITVM4(); } else { WAITVM2(); }
    BAR();
#pragma unroll
    for (int ct = 0; ct < 4; ++ct)
#pragma unroll
      for (int ks = 0; ks < 2; ++ks)
        bv[ct][ks] = *(const f16x8*)&Bh1[(qwc + ct * 16 + mm) * 64 +
                                         (((ks * 4 + q) ^ mm7)) * 8];
    if (t < 7) stageU(Brow, 0, t + 1, nBh0, w, srow8, kg8);
    LGKM0();
    PRIO1();
#pragma unroll
    for (int rt = 0; rt < 2; ++rt)
#pragma unroll
      for (int ct = 0; ct < 4; ++ct)
#pragma unroll
        for (int ks = 0; ks < 2; ++ks)
          acc[0][1][rt][ct] = mfma_16x16x32(af[rt][ks], bv[ct][ks],
                                            acc[0][1][rt][ct]);
    PRIO0();
    SCHEDFENCE();

    // ---- phase 2: quadrant (qm1, qn1) — bv held, read A half 1 ----
    if (t < 7) { WAITVM4(); } else { WAITVM0(); }
    BAR();
#pragma unroll
    for (int rt = 0; rt < 2; ++rt)
#pragma unroll
      for (int ks = 0; ks < 2; ++ks)
        af[rt][ks] = *(const f16x8*)&Ah1[(qwr + rt * 16 + mm) * 64 +
                                         (((ks * 4 + q) ^ mm7)) * 8];
    if (t < 7) stageU(Brow, 1, t + 1, nBh1, w, srow8, kg8);
    LGKM0();
    PRIO1();
#pragma unroll
    for (int rt = 0; rt < 2; ++rt)
#pragma unroll
      for (int ct = 0; ct < 4; ++ct)
#pragma unroll
        for (int ks = 0; ks < 2; ++ks)
          acc[1][1][rt][ct] = mfma_16x16x32(af[rt][ks], bv[ct][ks],
                                            acc[1][1][rt][ct]);
    PRIO0();
    SCHEDFENCE();

    // ---- phase 3: quadrant (qm1, qn0) — af held, re-read B half 0 ----
    BAR();
#pragma unroll
    for (int ct = 0; ct < 4; ++ct)
#pragma unroll
      for (int ks = 0; ks < 2; ++ks)
        bv[ct][ks] = *(const f16x8*)&Bh0[(qwc + ct * 16 + mm) * 64 +
                                         (((ks * 4 + q) ^ mm7)) * 8];
    if (t < 7) stageU(Arow, 1, t + 1, nAh1, w, srow8, kg8);
    LGKM0();
    PRIO1();
#pragma unroll
    for (int rt = 0; rt < 2; ++rt)
#pragma unroll
      for (int ct = 0; ct < 4; ++ct)
#pragma unroll
        for (int ks = 0; ks < 2; ++ks)
          acc[1][0][rt][ct] = mfma_16x16x32(af[rt][ks], bv[ct][ks],
                                            acc[1][0][rt][ct]);
    PRIO0();
    SCHEDFENCE();
  }
}

// ---- layer 0: h0 = relu(emb . W0T^T + b0), f16 out. 256x256 8-phase. ----
__global__ __launch_bounds__(512) void kgemm1(const f16* __restrict__ emb,
                                              const f16* __restrict__ W0T,
                                              const float* __restrict__ small,
                                              f16* __restrict__ h0,
                                              int Nc) {
  __shared__ f16 smem[65536];  // A 64KB | B 64KB; epilogue Cst aliases base
  const int b  = blockIdx.x;
  const int p  = b & 15;
  const int ht = (b >> 4) & 1;
  const int nt = b >> 5;
  const int n0 = nt * 256;
  const int hc0 = ht * 256;
  const int tid = threadIdx.x;
  const int w = tid >> 6;
  const int lane = tid & 63;
  const int q = lane >> 4;
  const int mm = lane & 15;

  const f16* Arow = emb + (size_t)n0 * 512;
  const f16* Brow = W0T + ((size_t)p << 18) + (size_t)hc0 * 512;

  floatx4 acc[2][2][2][4];
#pragma unroll
  for (int i = 0; i < 2; ++i)
#pragma unroll
    for (int j = 0; j < 2; ++j)
#pragma unroll
      for (int k = 0; k < 2; ++k)
#pragma unroll
        for (int l = 0; l < 4; ++l) acc[i][j][k][l] = floatx4{0.f, 0.f, 0.f, 0.f};

  gemm_core(Arow, Brow, smem, acc, w, lane);

  // epilogue: bias+relu+f16, LDS bounce (Cst 64x264), 4 passes of 64 rows
  __syncthreads();
  f16* Cst = smem;
#pragma unroll
  for (int P = 0; P < 4; ++P) {
    if (((w & 3) >> 1) == (P & 1)) {
#pragma unroll
      for (int qn = 0; qn < 2; ++qn)
#pragma unroll
        for (int ct = 0; ct < 4; ++ct) {
          const int col = qn * 128 + (w >> 2) * 64 + ct * 16 + mm;
          const float bvv = small[p * 512 + hc0 + col];
#pragma unroll
          for (int rt = 0; rt < 2; ++rt)
#pragma unroll
            for (int r = 0; r < 4; ++r) {
              float v = acc[P >> 1][qn][rt][ct][r] + bvv;
              v = v > 0.f ? v : 0.f;
              Cst[((w & 1) * 32 + rt * 16 + q * 4 + r) * 264 + col] = (f16)v;
            }
        }
    }
    __syncthreads();
#pragma unroll
    for (int k = 0; k < 4; ++k) {
      const int idx = tid + k * 512;
      const int row = idx >> 5;
      const int ch  = idx & 31;
      uint4 v = *(const uint4*)&Cst[row * 264 + ch * 8];
      *(uint4*)&h0[((size_t)p * Nc + n0 + P * 64 + row) * 512 + hc0 + ch * 8] = v;
    }
    if (P < 3) __syncthreads();
  }
}

// ---- layer 1 GEMM + fused partial layer-2 dot. 256x256 8-phase. ----
__global__ __launch_bounds__(512) void kgemm2(const f16* __restrict__ h0,
                                              const f16* __restrict__ W1T,
                                              const float* __restrict__ small,
                                              float* __restrict__ pacc,
                                              int Nc) {
  __shared__ f16 smem[65536];
  __shared__ float oacc[256];
  int p, ht, nt;
  decode_block2(blockIdx.x, gridDim.x, p, ht, nt);
  const int n0 = nt * 256;
  const int hc0 = ht * 256;
  const int tid = threadIdx.x;
  const int w = tid >> 6;
  const int lane = tid & 63;
  const int q = lane >> 4;
  const int mm = lane & 15;
  if (tid < 256) oacc[tid] = 0.f;

  const f16* Arow = h0 + ((size_t)p * Nc + n0) * 512;
  const f16* Brow = W1T + ((size_t)p << 18) + (size_t)hc0 * 512;

  floatx4 acc[2][2][2][4];
#pragma unroll
  for (int i = 0; i < 2; ++i)
#pragma unroll
    for (int j = 0; j < 2; ++j)
#pragma unroll
      for (int k = 0; k < 2; ++k)
#pragma unroll
        for (int l = 0; l < 4; ++l) acc[i][j][k][l] = floatx4{0.f, 0.f, 0.f, 0.f};

  gemm_core(Arow, Brow, smem, acc, w, lane);

  // epilogue: h1 = relu(acc + b1); pd[row] += h1 * W2[col]; reduce over mm
  __syncthreads();
#pragma unroll
  for (int qm = 0; qm < 2; ++qm) {
    float pd[2][4];
#pragma unroll
    for (int rt = 0; rt < 2; ++rt)
#pragma unroll
      for (int r = 0; r < 4; ++r) pd[rt][r] = 0.f;
#pragma unroll
    for (int qn = 0; qn < 2; ++qn)
#pragma unroll
      for (int ct = 0; ct < 4; ++ct) {
        const int col = hc0 + qn * 128 + (w >> 2) * 64 + ct * 16 + mm;
        const float b1v = small[8192 + p * 512 + col];
        const float w2v = small[16384 + p * 512 + col];
#pragma unroll
        for (int rt = 0; rt < 2; ++rt)
#pragma unroll
          for (int r = 0; r < 4; ++r) {
            float v = acc[qm][qn][rt][ct][r] + b1v;
            v = v > 0.f ? v : 0.f;
            pd[rt][r] += v * w2v;
          }
      }
#pragma unroll
    for (int rt = 0; rt < 2; ++rt)
#pragma unroll
      for (int r = 0; r < 4; ++r) {
        float v = pd[rt][r];
        v += __shfl_xor(v, 1, 16);
        v += __shfl_xor(v, 2, 16);
        v += __shfl_xor(v, 4, 16);
        v += __shfl_xor(v, 8, 16);
        if (mm == 0)
          atomicAdd(&oacc[qm * 128 + (w & 3) * 32 + rt * 16 + q * 4 + r], v);
      }
  }
  __syncthreads();
  if (tid < 256)
    pacc[(size_t)(p * 2 + ht) * Nc + n0 + tid] = oacc[tid];
}

// ---- finish: sum 2 ht partials + b2, sigmoid, fp32 out ----
__global__ __launch_bounds__(256) void kfin(const float* __restrict__ pacc,
                                            const float* __restrict__ small,
                                            float* __restrict__ out, int Nc) {
  const int idx = blockIdx.x * 256 + threadIdx.x;
  if (idx >= Nc * 16) return;
  const int n = idx >> 4;
  const int p = idx & 15;
  float v = small[24576 + p];
#pragma unroll
  for (int ht = 0; ht < 2; ++ht) v += pacc[(size_t)(p * 2 + ht) * Nc + n];
  out[(size_t)n * 16 + p] = 1.f / (1.f + expf(-v));
}

// ---- fallback (tiny ws / odd N): slow but correct, fp32 in/out ----
__global__ __launch_bounds__(64) void knaive(const float* __restrict__ emb,
                                             const float* __restrict__ W0,
                                             const float* __restrict__ b0,
                                             const float* __restrict__ W1,
                                             const float* __restrict__ b1,
                                             const float* __restrict__ W2,
                                             const float* __restrict__ b2,
                                             float* __restrict__ out) {
  const int n = blockIdx.x >> 4;
  const int p = blockIdx.x & 15;
  __shared__ float h0s[512];
  __shared__ float h1s[512];
  const size_t wb = (size_t)p << 18;
  const int t = threadIdx.x;
  for (int h = t; h < 512; h += 64) {
    float a = 0.f;
    for (int e = 0; e < 512; ++e)
      a += emb[(size_t)n * 512 + e] * W0[wb + (size_t)e * 512 + h];
    a += b0[p * 512 + h];
    h0s[h] = a > 0.f ? a : 0.f;
  }
  __syncthreads();
  for (int k = t; k < 512; k += 64) {
    float a = 0.f;
    for (int hh = 0; hh < 512; ++hh)
      a += h0s[hh] * W1[wb + (size_t)hh * 512 + k];
    a += b1[p * 512 + k];
    h1s[k] = a > 0.f ? a : 0.f;
  }
  __syncthreads();
  float s = 0.f;
  for (int k = t; k < 512; k += 64) s += h1s[k] * W2[p * 512 + k];
  for (int off = 32; off; off >>= 1) s += __shfl_down(s, off, 64);
  if (t == 0)
    out[(size_t)n * 16 + p] = 1.f / (1.f + expf(-(s + b2[p])));
}

extern "C" void kernel_launch(void* const* d_in, const int* in_sizes, int n_in,
                              void* d_out, int out_size, void* d_ws, size_t ws_size,
                              hipStream_t stream) {
  (void)n_in; (void)out_size;
  const float* emb = (const float*)d_in[0];
  const float* W0  = (const float*)d_in[1];
  const float* b0  = (const float*)d_in[2];
  const float* W1  = (const float*)d_in[3];
  const float* b1  = (const float*)d_in[4];
  const float* W2  = (const float*)d_in[5];
  const float* b2  = (const float*)d_in[6];
  float* out = (float*)d_out;

  const int N = in_sizes[0] / 512;

  char* ws = (char*)d_ws;
  f16*   W0T    = (f16*)ws;                                  // 8 MB
  f16*   W1T    = (f16*)(ws + (8ll << 20));                  // 8 MB
  float* smallF = (float*)(ws + (16ll << 20));               // 128 KB
  float* pacc   = (float*)(ws + (16ll << 20) + 131072);      // <=256*N B slot
  f16*   embB   = (f16*)(ws + (16ll << 20) + 131072 + (size_t)N * 256);
  f16*   h0     = (f16*)(ws + (16ll << 20) + 131072 + (size_t)N * 256 +
                         (size_t)N * 1024);
  const long long fixed = (16ll << 20) + 131072 + (long long)N * 256 +
                          (long long)N * 1024;
  long long avail = (long long)ws_size - fixed;
  long long rows = avail > 0 ? avail / (16 * 512 * 2) : 0;
  int Nc = (int)((rows / 256) * 256);
  if (Nc > N) Nc = N;

  if (Nc < 256 || (N % 256) != 0) {
    knaive<<<dim3(N * PDIM), dim3(64), 0, stream>>>(emb, W0, b0, W1, b1, W2,
                                                    b2, out);
    return;
  }

  const int n8 = N * 512 / 8;
  const int nConvBlk = (n8 + 255) / 256;
  kprep<<<dim3(2048 + nConvBlk + 97), dim3(256), 0, stream>>>(
      emb, W0, W1, b0, b1, W2, b2, embB, W0T, W1T, smallF, n8, nConvBlk);

  for (int noff = 0; noff < N; noff += Nc) {
    const int cur = (N - noff < Nc) ? (N - noff) : Nc;
    kgemm1<<<dim3(32 * (cur / 256)), dim3(512), 0, stream>>>(
        embB + (size_t)noff * 512, W0T, smallF, h0, cur);
    kgemm2<<<dim3(32 * (cur / 256)), dim3(512), 0, stream>>>(
        h0, W1T, smallF, pacc, cur);
    kfin<<<dim3((cur * 16 + 255) / 256), dim3(256), 0, stream>>>(
        pacc, smallF, out + (size_t)noff * 16, cur);
  }
}

// Round 10
// 243.068 us; speedup vs baseline: 1.1636x; 1.0175x over previous
//
#include <hip/hip_runtime.h>
#include <stdint.h>

typedef _Float16 f16;
typedef _Float16 f16x8 __attribute__((ext_vector_type(8)));
typedef float floatx4 __attribute__((ext_vector_type(4)));
typedef unsigned short u16;

#define PDIM 16

__device__ __forceinline__ floatx4 mfma_16x16x32(f16x8 a, f16x8 b, floatx4 c) {
  return __builtin_amdgcn_mfma_f32_16x16x32_f16(a, b, c, 0, 0, 0);
}

// async 16B/lane global->LDS; LDS dst = wave-uniform base + lane*16.
__device__ __forceinline__ void stage16(const f16* g, f16* lds_base) {
  __builtin_amdgcn_global_load_lds(
      (const __attribute__((address_space(1))) void*)g,
      (__attribute__((address_space(3))) void*)lds_base, 16, 0, 0);
}

#define WAITVM4() asm volatile("s_waitcnt vmcnt(4)" ::: "memory")
#define WAITVM2() asm volatile("s_waitcnt vmcnt(2)" ::: "memory")
#define WAITVM0() asm volatile("s_waitcnt vmcnt(0)" ::: "memory")
#define BAR()     asm volatile("s_barrier" ::: "memory")
#define LGKM0()   asm volatile("s_waitcnt lgkmcnt(0)" ::: "memory")
#define SCHEDFENCE() __builtin_amdgcn_sched_barrier(0)
#define PRIO1() __builtin_amdgcn_s_setprio(1)
#define PRIO0() __builtin_amdgcn_s_setprio(0)

// ===================== 8-phase 256x256 GEMM core (R9, verified) ============
// 2-barrier structure was pinned at ~105us (654 TF). This quadrant-phased
// schedule (m201-style) measured 94us kgemm1 (R9): BM=BN=256, BK=64, 8 waves,
// derived counted vmcnt(4) (loads in flight across barriers), per-phase
// {vmcnt; bar; ds_read; issue 1 unit; lgkm0; prio1; 16 MFMA; prio0; fence}.
// K accumulation order identical to 2-phase -> bit-identical h0.
// ==========================================================================

// XCD-affinity decode for kgemm2 (A = h0[p] is per-p; measured win).
__device__ __forceinline__ void decode_block2(int b, int nwg, int& p, int& ht,
                                              int& nt) {
  const int NT = nwg >> 5;  // number of 256-row n-tiles
  if ((NT & 7) == 0) {
    const int x  = b & 7;
    const int u  = b >> 3;
    const int i  = u & 31;     // 8 ntl x 2 pl x 2 ht
    const int cg = u >> 5;
    ht = i & 1;
    const int pl  = (i >> 1) & 1;
    const int ntl = i >> 2;
    p  = x * 2 + pl;
    nt = cg * 8 + ntl;
  } else {
    p  = b & 15;
    ht = (b >> 4) & 1;
    nt = b >> 5;
  }
}

// ---- fused prep ----
// [0,256): W0/W1 transpose via XOR-swizzled LDS panel (R9 register-only
//   version had 64-line scattered global writes = ~50us; this has BOTH sides
//   coalesced). Block = 64h x 512e panel. LDS word (e,hp) at
//   e*32 + (hp ^ ((e>>3)&31)): read-out gather bank = hp ^ chunk -> bijective
//   over 32 lanes (conflict-free); global writes lane-consecutive uint4.
// [256,256+nConvBlk): emb fp32->f16. Then biases+W2 pack (fp32).
__global__ __launch_bounds__(256) void kprep(const float* __restrict__ emb,
                                             const float* __restrict__ W0,
                                             const float* __restrict__ W1,
                                             const float* __restrict__ b0,
                                             const float* __restrict__ b1,
                                             const float* __restrict__ W2,
                                             const float* __restrict__ b2,
                                             f16* __restrict__ embB,
                                             f16* __restrict__ W0T,
                                             f16* __restrict__ W1T,
                                             float* __restrict__ smallF,
                                             int n8, int nConvBlk) {
  __shared__ unsigned int tile[16384];  // 512 rows x 32 h-pair words = 64 KB
  const int b = blockIdx.x;
  const int t = threadIdx.x;
  if (b < 256) {
    const int m  = b >> 7;         // 0: W0, 1: W1
    const int p  = (b >> 3) & 15;
    const int tc = b & 7;          // h-tile (64 h)
    const int hb = tc * 64;
    const float* src = (m ? W1 : W0) + ((size_t)p << 18);
    f16*         dst = (m ? W1T : W0T) + ((size_t)p << 18);
    const int er = t >> 2;         // base e-row 0..63
    const int hq = t & 3;
#pragma unroll
    for (int j = 0; j < 8; ++j) {
      const int e   = er + j * 64;
      const int swz = (e >> 3) & 31;
      const float* rp = src + (size_t)e * 512 + hb;
#pragma unroll
      for (int i = 0; i < 4; ++i) {
        const int hc = hq * 4 + i * 16;   // lanes 0-3 cover 64B contiguous
        float4 v = *(const float4*)(rp + hc);
        union { f16 h2[2]; unsigned int u; } w0, w1;
        w0.h2[0] = (f16)v.x; w0.h2[1] = (f16)v.y;
        w1.h2[0] = (f16)v.z; w1.h2[1] = (f16)v.w;
        const int hp = hc >> 1;           // even
        tile[e * 32 + (hp ^ swz)]       = w0.u;
        tile[e * 32 + ((hp + 1) ^ swz)] = w1.u;
      }
    }
    __syncthreads();
    const int w = t >> 6, l = t & 63;
#pragma unroll
    for (int P = 0; P < 16; ++P) {
      const int hl  = P * 4 + w;
      const int hp  = hl >> 1;
      const int sub = hl & 1;
      union { u16 uu[8]; uint4 v; } o;
#pragma unroll
      for (int j = 0; j < 8; ++j) {
        const int e = l * 8 + j;
        const unsigned int word = tile[e * 32 + (hp ^ ((e >> 3) & 31))];
        o.uu[j] = (u16)(sub ? (word >> 16) : (word & 0xffffu));
      }
      *(uint4*)(dst + (size_t)(hb + hl) * 512 + l * 8) = o.v;
    }
  } else if (b < 256 + nConvBlk) {
    const int i = (b - 256) * 256 + t;
    if (i < n8) {
      const float4* s = (const float4*)emb;
      float4 a = s[i * 2], bb = s[i * 2 + 1];
      union { f16 h[8]; uint4 v; } o;
      o.h[0] = (f16)a.x;  o.h[1] = (f16)a.y;  o.h[2] = (f16)a.z;  o.h[3] = (f16)a.w;
      o.h[4] = (f16)bb.x; o.h[5] = (f16)bb.y; o.h[6] = (f16)bb.z; o.h[7] = (f16)bb.w;
      *(uint4*)(embB + (size_t)i * 8) = o.v;
    }
  } else {
    const int j = (b - 256 - nConvBlk) * 256 + t;
    if (j < 24592) {
      const float* src;
      int off;
      if (j < 8192)       { src = b0; off = j; }
      else if (j < 16384) { src = b1; off = j - 8192; }
      else if (j < 24576) { src = W2; off = j - 16384; }
      else                { src = b2; off = j - 24576; }
      smallF[j] = src[off];
    }
  }
}

// stage one (matrix, half) unit: 16 KB, 2 loads per thread, fixed order.
__device__ __forceinline__ void stageU(const f16* M, int h, int tt, f16* buf,
                                       int w, int srow8, int kg8) {
  stage16(M + (size_t)(h * 128 + w * 8 + srow8) * 512 + tt * 64 + kg8,
          buf + (w * 8) * 64);
  stage16(M + (size_t)(h * 128 + 64 + w * 8 + srow8) * 512 + tt * 64 + kg8,
          buf + (64 + w * 8) * 64);
}

__device__ __forceinline__ void gemm_core(const f16* __restrict__ Arow,
                                          const f16* __restrict__ Brow,
                                          f16* smem, floatx4 (*acc)[2][2][4],
                                          int w, int lane) {
  const int q   = lane >> 4;
  const int mm  = lane & 15;
  const int mm7 = mm & 7;
  const int qwr = (w & 3) * 32;
  const int qwc = (w >> 2) * 64;
  const int srow8 = lane >> 3;
  const int kg8   = (((lane & 7) ^ ((lane >> 3) & 7)) * 8);

  // prologue: tile 0 units in first-use order [A0, B0, B1, A1]
  stageU(Arow, 0, 0, smem + 0 * 8192, w, srow8, kg8);
  stageU(Brow, 0, 0, smem + 32768 + 0 * 8192, w, srow8, kg8);
  stageU(Brow, 1, 0, smem + 32768 + 1 * 8192, w, srow8, kg8);
  stageU(Arow, 1, 0, smem + 1 * 8192, w, srow8, kg8);

  f16x8 af[2][2], bv[4][2];

  for (int t = 0; t < 8; ++t) {
    const int cb = t & 1;
    const f16* Ah0 = smem + (cb * 2 + 0) * 8192;
    const f16* Ah1 = smem + (cb * 2 + 1) * 8192;
    const f16* Bh0 = smem + 32768 + (cb * 2 + 0) * 8192;
    const f16* Bh1 = smem + 32768 + (cb * 2 + 1) * 8192;
    const int nb = cb ^ 1;
    f16* nAh0 = smem + (nb * 2 + 0) * 8192;
    f16* nAh1 = smem + (nb * 2 + 1) * 8192;
    f16* nBh0 = smem + 32768 + (nb * 2 + 0) * 8192;
    f16* nBh1 = smem + 32768 + (nb * 2 + 1) * 8192;

    // ---- phase 0: quadrant (0,0) ----
    WAITVM4();
    BAR();
#pragma unroll
    for (int rt = 0; rt < 2; ++rt)
#pragma unroll
      for (int ks = 0; ks < 2; ++ks)
        af[rt][ks] = *(const f16x8*)&Ah0[(qwr + rt * 16 + mm) * 64 +
                                         (((ks * 4 + q) ^ mm7)) * 8];
#pragma unroll
    for (int ct = 0; ct < 4; ++ct)
#pragma unroll
      for (int ks = 0; ks < 2; ++ks)
        bv[ct][ks] = *(const f16x8*)&Bh0[(qwc + ct * 16 + mm) * 64 +
                                         (((ks * 4 + q) ^ mm7)) * 8];
    if (t < 7) stageU(Arow, 0, t + 1, nAh0, w, srow8, kg8);
    LGKM0();
    PRIO1();
#pragma unroll
    for (int rt = 0; rt < 2; ++rt)
#pragma unroll
      for (int ct = 0; ct < 4; ++ct)
#pragma unroll
        for (int ks = 0; ks < 2; ++ks)
          acc[0][0][rt][ct] = mfma_16x16x32(af[rt][ks], bv[ct][ks],
                                            acc[0][0][rt][ct]);
    PRIO0();
    SCHEDFENCE();

    // ---- phase 1: quadrant (0,1) — af held, read B half 1 ----
    if (t < 7) { WAITVM4(); } else { WAITVM2(); }
    BAR();
#pragma unroll
    for (int ct = 0; ct < 4; ++ct)
#pragma unroll
      for (int ks = 0; ks < 2; ++ks)
        bv[ct][ks] = *(const f16x8*)&Bh1[(qwc + ct * 16 + mm) * 64 +
                                         (((ks * 4 + q) ^ mm7)) * 8];
    if (t < 7) stageU(Brow, 0, t + 1, nBh0, w, srow8, kg8);
    LGKM0();
    PRIO1();
#pragma unroll
    for (int rt = 0; rt < 2; ++rt)
#pragma unroll
      for (int ct = 0; ct < 4; ++ct)
#pragma unroll
        for (int ks = 0; ks < 2; ++ks)
          acc[0][1][rt][ct] = mfma_16x16x32(af[rt][ks], bv[ct][ks],
                                            acc[0][1][rt][ct]);
    PRIO0();
    SCHEDFENCE();

    // ---- phase 2: quadrant (1,1) — bv held, read A half 1 ----
    if (t < 7) { WAITVM4(); } else { WAITVM0(); }
    BAR();
#pragma unroll
    for (int rt = 0; rt < 2; ++rt)
#pragma unroll
      for (int ks = 0; ks < 2; ++ks)
        af[rt][ks] = *(const f16x8*)&Ah1[(qwr + rt * 16 + mm) * 64 +
                                         (((ks * 4 + q) ^ mm7)) * 8];
    if (t < 7) stageU(Brow, 1, t + 1, nBh1, w, srow8, kg8);
    LGKM0();
    PRIO1();
#pragma unroll
    for (int rt = 0; rt < 2; ++rt)
#pragma unroll
      for (int ct = 0; ct < 4; ++ct)
#pragma unroll
        for (int ks = 0; ks < 2; ++ks)
          acc[1][1][rt][ct] = mfma_16x16x32(af[rt][ks], bv[ct][ks],
                                            acc[1][1][rt][ct]);
    PRIO0();
    SCHEDFENCE();

    // ---- phase 3: quadrant (1,0) — af held, re-read B half 0 ----
    BAR();
#pragma unroll
    for (int ct = 0; ct < 4; ++ct)
#pragma unroll
      for (int ks = 0; ks < 2; ++ks)
        bv[ct][ks] = *(const f16x8*)&Bh0[(qwc + ct * 16 + mm) * 64 +
                                         (((ks * 4 + q) ^ mm7)) * 8];
    if (t < 7) stageU(Arow, 1, t + 1, nAh1, w, srow8, kg8);
    LGKM0();
    PRIO1();
#pragma unroll
    for (int rt = 0; rt < 2; ++rt)
#pragma unroll
      for (int ct = 0; ct < 4; ++ct)
#pragma unroll
        for (int ks = 0; ks < 2; ++ks)
          acc[1][0][rt][ct] = mfma_16x16x32(af[rt][ks], bv[ct][ks],
                                            acc[1][0][rt][ct]);
    PRIO0();
    SCHEDFENCE();
  }
}

// ---- layer 0: h0 = relu(emb . W0T^T + b0), f16 out. 256x256 8-phase. ----
__global__ __launch_bounds__(512) void kgemm1(const f16* __restrict__ emb,
                                              const f16* __restrict__ W0T,
                                              const float* __restrict__ small,
                                              f16* __restrict__ h0,
                                              int Nc) {
  __shared__ f16 smem[65536];  // A 64KB | B 64KB; epilogue Cst aliases base
  const int b  = blockIdx.x;
  const int p  = b & 15;
  const int ht = (b >> 4) & 1;
  const int nt = b >> 5;
  const int n0 = nt * 256;
  const int hc0 = ht * 256;
  const int tid = threadIdx.x;
  const int w = tid >> 6;
  const int lane = tid & 63;
  const int q = lane >> 4;
  const int mm = lane & 15;

  const f16* Arow = emb + (size_t)n0 * 512;
  const f16* Brow = W0T + ((size_t)p << 18) + (size_t)hc0 * 512;

  floatx4 acc[2][2][2][4];
#pragma unroll
  for (int i = 0; i < 2; ++i)
#pragma unroll
    for (int j = 0; j < 2; ++j)
#pragma unroll
      for (int k = 0; k < 2; ++k)
#pragma unroll
        for (int l = 0; l < 4; ++l) acc[i][j][k][l] = floatx4{0.f, 0.f, 0.f, 0.f};

  gemm_core(Arow, Brow, smem, acc, w, lane);

  // epilogue: bias+relu+f16, LDS bounce (Cst 64x264), 4 passes of 64 rows
  __syncthreads();
  f16* Cst = smem;
#pragma unroll
  for (int P = 0; P < 4; ++P) {
    if (((w & 3) >> 1) == (P & 1)) {
#pragma unroll
      for (int qn = 0; qn < 2; ++qn)
#pragma unroll
        for (int ct = 0; ct < 4; ++ct) {
          const int col = qn * 128 + (w >> 2) * 64 + ct * 16 + mm;
          const float bvv = small[p * 512 + hc0 + col];
#pragma unroll
          for (int rt = 0; rt < 2; ++rt)
#pragma unroll
            for (int r = 0; r < 4; ++r) {
              float v = acc[P >> 1][qn][rt][ct][r] + bvv;
              v = v > 0.f ? v : 0.f;
              Cst[((w & 1) * 32 + rt * 16 + q * 4 + r) * 264 + col] = (f16)v;
            }
        }
    }
    __syncthreads();
#pragma unroll
    for (int k = 0; k < 4; ++k) {
      const int idx = tid + k * 512;
      const int row = idx >> 5;
      const int ch  = idx & 31;
      uint4 v = *(const uint4*)&Cst[row * 264 + ch * 8];
      *(uint4*)&h0[((size_t)p * Nc + n0 + P * 64 + row) * 512 + hc0 + ch * 8] = v;
    }
    if (P < 3) __syncthreads();
  }
}

// ---- layer 1 GEMM + fused partial layer-2 dot. 256x256 8-phase. ----
__global__ __launch_bounds__(512) void kgemm2(const f16* __restrict__ h0,
                                              const f16* __restrict__ W1T,
                                              const float* __restrict__ small,
                                              float* __restrict__ pacc,
                                              int Nc) {
  __shared__ f16 smem[65536];
  __shared__ float oacc[256];
  int p, ht, nt;
  decode_block2(blockIdx.x, gridDim.x, p, ht, nt);
  const int n0 = nt * 256;
  const int hc0 = ht * 256;
  const int tid = threadIdx.x;
  const int w = tid >> 6;
  const int lane = tid & 63;
  const int q = lane >> 4;
  const int mm = lane & 15;
  if (tid < 256) oacc[tid] = 0.f;

  const f16* Arow = h0 + ((size_t)p * Nc + n0) * 512;
  const f16* Brow = W1T + ((size_t)p << 18) + (size_t)hc0 * 512;

  floatx4 acc[2][2][2][4];
#pragma unroll
  for (int i = 0; i < 2; ++i)
#pragma unroll
    for (int j = 0; j < 2; ++j)
#pragma unroll
      for (int k = 0; k < 2; ++k)
#pragma unroll
        for (int l = 0; l < 4; ++l) acc[i][j][k][l] = floatx4{0.f, 0.f, 0.f, 0.f};

  gemm_core(Arow, Brow, smem, acc, w, lane);

  // epilogue: h1 = relu(acc + b1); pd[row] += h1 * W2[col]; reduce over mm
  __syncthreads();
#pragma unroll
  for (int qm = 0; qm < 2; ++qm) {
    float pd[2][4];
#pragma unroll
    for (int rt = 0; rt < 2; ++rt)
#pragma unroll
      for (int r = 0; r < 4; ++r) pd[rt][r] = 0.f;
#pragma unroll
    for (int qn = 0; qn < 2; ++qn)
#pragma unroll
      for (int ct = 0; ct < 4; ++ct) {
        const int col = hc0 + qn * 128 + (w >> 2) * 64 + ct * 16 + mm;
        const float b1v = small[8192 + p * 512 + col];
        const float w2v = small[16384 + p * 512 + col];
#pragma unroll
        for (int rt = 0; rt < 2; ++rt)
#pragma unroll
          for (int r = 0; r < 4; ++r) {
            float v = acc[qm][qn][rt][ct][r] + b1v;
            v = v > 0.f ? v : 0.f;
            pd[rt][r] += v * w2v;
          }
      }
#pragma unroll
    for (int rt = 0; rt < 2; ++rt)
#pragma unroll
      for (int r = 0; r < 4; ++r) {
        float v = pd[rt][r];
        v += __shfl_xor(v, 1, 16);
        v += __shfl_xor(v, 2, 16);
        v += __shfl_xor(v, 4, 16);
        v += __shfl_xor(v, 8, 16);
        if (mm == 0)
          atomicAdd(&oacc[qm * 128 + (w & 3) * 32 + rt * 16 + q * 4 + r], v);
      }
  }
  __syncthreads();
  if (tid < 256)
    pacc[(size_t)(p * 2 + ht) * Nc + n0 + tid] = oacc[tid];
}

// ---- finish: sum 2 ht partials + b2, sigmoid, fp32 out ----
__global__ __launch_bounds__(256) void kfin(const float* __restrict__ pacc,
                                            const float* __restrict__ small,
                                            float* __restrict__ out, int Nc) {
  const int idx = blockIdx.x * 256 + threadIdx.x;
  if (idx >= Nc * 16) return;
  const int n = idx >> 4;
  const int p = idx & 15;
  float v = small[24576 + p];
#pragma unroll
  for (int ht = 0; ht < 2; ++ht) v += pacc[(size_t)(p * 2 + ht) * Nc + n];
  out[(size_t)n * 16 + p] = 1.f / (1.f + expf(-v));
}

// ---- fallback (tiny ws / odd N): slow but correct, fp32 in/out ----
__global__ __launch_bounds__(64) void knaive(const float* __restrict__ emb,
                                             const float* __restrict__ W0,
                                             const float* __restrict__ b0,
                                             const float* __restrict__ W1,
                                             const float* __restrict__ b1,
                                             const float* __restrict__ W2,
                                             const float* __restrict__ b2,
                                             float* __restrict__ out) {
  const int n = blockIdx.x >> 4;
  const int p = blockIdx.x & 15;
  __shared__ float h0s[512];
  __shared__ float h1s[512];
  const size_t wb = (size_t)p << 18;
  const int t = threadIdx.x;
  for (int h = t; h < 512; h += 64) {
    float a = 0.f;
    for (int e = 0; e < 512; ++e)
      a += emb[(size_t)n * 512 + e] * W0[wb + (size_t)e * 512 + h];
    a += b0[p * 512 + h];
    h0s[h] = a > 0.f ? a : 0.f;
  }
  __syncthreads();
  for (int k = t; k < 512; k += 64) {
    float a = 0.f;
    for (int hh = 0; hh < 512; ++hh)
      a += h0s[hh] * W1[wb + (size_t)hh * 512 + k];
    a += b1[p * 512 + k];
    h1s[k] = a > 0.f ? a : 0.f;
  }
  __syncthreads();
  float s = 0.f;
  for (int k = t; k < 512; k += 64) s += h1s[k] * W2[p * 512 + k];
  for (int off = 32; off; off >>= 1) s += __shfl_down(s, off, 64);
  if (t == 0)
    out[(size_t)n * 16 + p] = 1.f / (1.f + expf(-(s + b2[p])));
}

extern "C" void kernel_launch(void* const* d_in, const int* in_sizes, int n_in,
                              void* d_out, int out_size, void* d_ws, size_t ws_size,
                              hipStream_t stream) {
  (void)n_in; (void)out_size;
  const float* emb = (const float*)d_in[0];
  const float* W0  = (const float*)d_in[1];
  const float* b0  = (const float*)d_in[2];
  const float* W1  = (const float*)d_in[3];
  const float* b1  = (const float*)d_in[4];
  const float* W2  = (const float*)d_in[5];
  const float* b2  = (const float*)d_in[6];
  float* out = (float*)d_out;

  const int N = in_sizes[0] / 512;

  char* ws = (char*)d_ws;
  f16*   W0T    = (f16*)ws;                                  // 8 MB
  f16*   W1T    = (f16*)(ws + (8ll << 20));                  // 8 MB
  float* smallF = (float*)(ws + (16ll << 20));               // 128 KB
  float* pacc   = (float*)(ws + (16ll << 20) + 131072);      // <=256*N B slot
  f16*   embB   = (f16*)(ws + (16ll << 20) + 131072 + (size_t)N * 256);
  f16*   h0     = (f16*)(ws + (16ll << 20) + 131072 + (size_t)N * 256 +
                         (size_t)N * 1024);
  const long long fixed = (16ll << 20) + 131072 + (long long)N * 256 +
                          (long long)N * 1024;
  long long avail = (long long)ws_size - fixed;
  long long rows = avail > 0 ? avail / (16 * 512 * 2) : 0;
  int Nc = (int)((rows / 256) * 256);
  if (Nc > N) Nc = N;

  if (Nc < 256 || (N % 256) != 0) {
    knaive<<<dim3(N * PDIM), dim3(64), 0, stream>>>(emb, W0, b0, W1, b1, W2,
                                                    b2, out);
    return;
  }

  const int n8 = N * 512 / 8;
  const int nConvBlk = (n8 + 255) / 256;
  kprep<<<dim3(256 + nConvBlk + 97), dim3(256), 0, stream>>>(
      emb, W0, W1, b0, b1, W2, b2, embB, W0T, W1T, smallF, n8, nConvBlk);

  for (int noff = 0; noff < N; noff += Nc) {
    const int cur = (N - noff < Nc) ? (N - noff) : Nc;
    kgemm1<<<dim3(32 * (cur / 256)), dim3(512), 0, stream>>>(
        embB + (size_t)noff * 512, W0T, smallF, h0, cur);
    kgemm2<<<dim3(32 * (cur / 256)), dim3(512), 0, stream>>>(
        h0, W1T, smallF, pacc, cur);
    kfin<<<dim3((cur * 16 + 255) / 256), dim3(256), 0, stream>>>(
        pacc, smallF, out + (size_t)noff * 16, cur);
  }
}

// Round 11
// 238.513 us; speedup vs baseline: 1.1858x; 1.0191x over previous
//
#include <hip/hip_runtime.h>
#include <stdint.h>

typedef _Float16 f16;
typedef _Float16 f16x8 __attribute__((ext_vector_type(8)));
typedef float floatx4 __attribute__((ext_vector_type(4)));
typedef unsigned short u16;

#define PDIM 16

__device__ __forceinline__ floatx4 mfma_16x16x32(f16x8 a, f16x8 b, floatx4 c) {
  return __builtin_amdgcn_mfma_f32_16x16x32_f16(a, b, c, 0, 0, 0);
}

// async 16B/lane global->LDS; LDS dst = wave-uniform base + lane*16.
__device__ __forceinline__ void stage16(const f16* g, f16* lds_base) {
  __builtin_amdgcn_global_load_lds(
      (const __attribute__((address_space(1))) void*)g,
      (__attribute__((address_space(3))) void*)lds_base, 16, 0, 0);
}

#define WAITVM4() asm volatile("s_waitcnt vmcnt(4)" ::: "memory")
#define WAITVM0() asm volatile("s_waitcnt vmcnt(0)" ::: "memory")
#define BAR()     asm volatile("s_barrier" ::: "memory")
#define SCHEDFENCE() __builtin_amdgcn_sched_barrier(0)
#define PRIO1() __builtin_amdgcn_s_setprio(1)
#define PRIO0() __builtin_amdgcn_s_setprio(0)

// ============ 2-section 256x256 GEMM core (R11; evolved from R9) ============
// R9's 4-phase/K-tile schedule measured 93us (vs 105 for 2-barrier): win came
// from counted vmcnt. Model: ~950cyc/phase of barrier-convoy on top of
// ~640cyc LDS + ~155cyc MFMA -> merge to 2 sections/K-tile (16 barriers per
// block instead of 32), with section-2's three read->MFMA chains interleaved
// so reads hide under the previous MFMA cluster. Unit issue order
// [A0,B0,B1,A1]; both section waits are exactly vmcnt(4). Same addresses,
// same per-acc K order -> bit-identical output; same register scheme
// (af 4 frags + bv 8 frags, serially reused) -> no spill risk.
// ===========================================================================

// XCD-affinity decode for kgemm2 (A = h0[p] is per-p; measured win).
__device__ __forceinline__ void decode_block2(int b, int nwg, int& p, int& ht,
                                              int& nt) {
  const int NT = nwg >> 5;  // number of 256-row n-tiles
  if ((NT & 7) == 0) {
    const int x  = b & 7;
    const int u  = b >> 3;
    const int i  = u & 31;     // 8 ntl x 2 pl x 2 ht
    const int cg = u >> 5;
    ht = i & 1;
    const int pl  = (i >> 1) & 1;
    const int ntl = i >> 2;
    p  = x * 2 + pl;
    nt = cg * 8 + ntl;
  } else {
    p  = b & 15;
    ht = (b >> 4) & 1;
    nt = b >> 5;
  }
}

// ---- fused prep ----
// [0,256): W0/W1 transpose via XOR-swizzled LDS panel, both sides coalesced.
// [256,256+nConvBlk): emb fp32->f16. Then biases+W2 pack (fp32).
__global__ __launch_bounds__(256) void kprep(const float* __restrict__ emb,
                                             const float* __restrict__ W0,
                                             const float* __restrict__ W1,
                                             const float* __restrict__ b0,
                                             const float* __restrict__ b1,
                                             const float* __restrict__ W2,
                                             const float* __restrict__ b2,
                                             f16* __restrict__ embB,
                                             f16* __restrict__ W0T,
                                             f16* __restrict__ W1T,
                                             float* __restrict__ smallF,
                                             int n8, int nConvBlk) {
  __shared__ unsigned int tile[16384];  // 512 rows x 32 h-pair words = 64 KB
  const int b = blockIdx.x;
  const int t = threadIdx.x;
  if (b < 256) {
    const int m  = b >> 7;         // 0: W0, 1: W1
    const int p  = (b >> 3) & 15;
    const int tc = b & 7;          // h-tile (64 h)
    const int hb = tc * 64;
    const float* src = (m ? W1 : W0) + ((size_t)p << 18);
    f16*         dst = (m ? W1T : W0T) + ((size_t)p << 18);
    const int er = t >> 2;         // base e-row 0..63
    const int hq = t & 3;
#pragma unroll
    for (int j = 0; j < 8; ++j) {
      const int e   = er + j * 64;
      const int swz = (e >> 3) & 31;
      const float* rp = src + (size_t)e * 512 + hb;
#pragma unroll
      for (int i = 0; i < 4; ++i) {
        const int hc = hq * 4 + i * 16;   // lanes 0-3 cover 64B contiguous
        float4 v = *(const float4*)(rp + hc);
        union { f16 h2[2]; unsigned int u; } w0, w1;
        w0.h2[0] = (f16)v.x; w0.h2[1] = (f16)v.y;
        w1.h2[0] = (f16)v.z; w1.h2[1] = (f16)v.w;
        const int hp = hc >> 1;           // even
        tile[e * 32 + (hp ^ swz)]       = w0.u;
        tile[e * 32 + ((hp + 1) ^ swz)] = w1.u;
      }
    }
    __syncthreads();
    const int w = t >> 6, l = t & 63;
#pragma unroll
    for (int P = 0; P < 16; ++P) {
      const int hl  = P * 4 + w;
      const int hp  = hl >> 1;
      const int sub = hl & 1;
      union { u16 uu[8]; uint4 v; } o;
#pragma unroll
      for (int j = 0; j < 8; ++j) {
        const int e = l * 8 + j;
        const unsigned int word = tile[e * 32 + (hp ^ ((e >> 3) & 31))];
        o.uu[j] = (u16)(sub ? (word >> 16) : (word & 0xffffu));
      }
      *(uint4*)(dst + (size_t)(hb + hl) * 512 + l * 8) = o.v;
    }
  } else if (b < 256 + nConvBlk) {
    const int i = (b - 256) * 256 + t;
    if (i < n8) {
      const float4* s = (const float4*)emb;
      float4 a = s[i * 2], bb = s[i * 2 + 1];
      union { f16 h[8]; uint4 v; } o;
      o.h[0] = (f16)a.x;  o.h[1] = (f16)a.y;  o.h[2] = (f16)a.z;  o.h[3] = (f16)a.w;
      o.h[4] = (f16)bb.x; o.h[5] = (f16)bb.y; o.h[6] = (f16)bb.z; o.h[7] = (f16)bb.w;
      *(uint4*)(embB + (size_t)i * 8) = o.v;
    }
  } else {
    const int j = (b - 256 - nConvBlk) * 256 + t;
    if (j < 24592) {
      const float* src;
      int off;
      if (j < 8192)       { src = b0; off = j; }
      else if (j < 16384) { src = b1; off = j - 8192; }
      else if (j < 24576) { src = W2; off = j - 16384; }
      else                { src = b2; off = j - 24576; }
      smallF[j] = src[off];
    }
  }
}

// stage one (matrix, half) unit: 16 KB, 2 loads per thread, fixed order.
__device__ __forceinline__ void stageU(const f16* M, int h, int tt, f16* buf,
                                       int w, int srow8, int kg8) {
  stage16(M + (size_t)(h * 128 + w * 8 + srow8) * 512 + tt * 64 + kg8,
          buf + (w * 8) * 64);
  stage16(M + (size_t)(h * 128 + 64 + w * 8 + srow8) * 512 + tt * 64 + kg8,
          buf + (64 + w * 8) * 64);
}

__device__ __forceinline__ void gemm_core(const f16* __restrict__ Arow,
                                          const f16* __restrict__ Brow,
                                          f16* smem, floatx4 (*acc)[2][2][4],
                                          int w, int lane) {
  const int q   = lane >> 4;
  const int mm  = lane & 15;
  const int mm7 = mm & 7;
  const int qwr = (w & 3) * 32;
  const int qwc = (w >> 2) * 64;
  const int srow8 = lane >> 3;
  const int kg8   = (((lane & 7) ^ ((lane >> 3) & 7)) * 8);

  // prologue: tile 0 units in issue order [A0, B0, B1, A1]
  stageU(Arow, 0, 0, smem + 0 * 8192, w, srow8, kg8);
  stageU(Brow, 0, 0, smem + 32768 + 0 * 8192, w, srow8, kg8);
  stageU(Brow, 1, 0, smem + 32768 + 1 * 8192, w, srow8, kg8);
  stageU(Arow, 1, 0, smem + 1 * 8192, w, srow8, kg8);

  f16x8 af[2][2], bv[4][2];

  for (int t = 0; t < 8; ++t) {
    const int cb = t & 1;
    const f16* Ah0 = smem + (cb * 2 + 0) * 8192;
    const f16* Ah1 = smem + (cb * 2 + 1) * 8192;
    const f16* Bh0 = smem + 32768 + (cb * 2 + 0) * 8192;
    const f16* Bh1 = smem + 32768 + (cb * 2 + 1) * 8192;
    const int nb = cb ^ 1;
    f16* nAh0 = smem + (nb * 2 + 0) * 8192;
    f16* nAh1 = smem + (nb * 2 + 1) * 8192;
    f16* nBh0 = smem + 32768 + (nb * 2 + 0) * 8192;
    f16* nBh1 = smem + 32768 + (nb * 2 + 1) * 8192;

    // ======== section 1: needs A0,B0 of t (oldest 4 loads) ========
    WAITVM4();
    SCHEDFENCE();
    BAR();
#pragma unroll
    for (int rt = 0; rt < 2; ++rt)
#pragma unroll
      for (int ks = 0; ks < 2; ++ks)
        af[rt][ks] = *(const f16x8*)&Ah0[(qwr + rt * 16 + mm) * 64 +
                                         (((ks * 4 + q) ^ mm7)) * 8];
#pragma unroll
    for (int ct = 0; ct < 4; ++ct)
#pragma unroll
      for (int ks = 0; ks < 2; ++ks)
        bv[ct][ks] = *(const f16x8*)&Bh0[(qwc + ct * 16 + mm) * 64 +
                                         (((ks * 4 + q) ^ mm7)) * 8];
    if (t < 7) {
      stageU(Arow, 0, t + 1, nAh0, w, srow8, kg8);
      stageU(Brow, 0, t + 1, nBh0, w, srow8, kg8);
    }
    PRIO1();
#pragma unroll
    for (int rt = 0; rt < 2; ++rt)
#pragma unroll
      for (int ct = 0; ct < 4; ++ct)
#pragma unroll
        for (int ks = 0; ks < 2; ++ks)
          acc[0][0][rt][ct] = mfma_16x16x32(af[rt][ks], bv[ct][ks],
                                            acc[0][0][rt][ct]);
    PRIO0();

    // ======== section 2: needs B1,A1 of t (next-oldest 4 loads) ========
    if (t < 7) { WAITVM4(); } else { WAITVM0(); }
    SCHEDFENCE();
    BAR();
    // chain 1: read Bh1 -> q01 (af held)
#pragma unroll
    for (int ct = 0; ct < 4; ++ct)
#pragma unroll
      for (int ks = 0; ks < 2; ++ks)
        bv[ct][ks] = *(const f16x8*)&Bh1[(qwc + ct * 16 + mm) * 64 +
                                         (((ks * 4 + q) ^ mm7)) * 8];
    if (t < 7) {
      stageU(Brow, 1, t + 1, nBh1, w, srow8, kg8);
      stageU(Arow, 1, t + 1, nAh1, w, srow8, kg8);
    }
    PRIO1();
#pragma unroll
    for (int rt = 0; rt < 2; ++rt)
#pragma unroll
      for (int ct = 0; ct < 4; ++ct)
#pragma unroll
        for (int ks = 0; ks < 2; ++ks)
          acc[0][1][rt][ct] = mfma_16x16x32(af[rt][ks], bv[ct][ks],
                                            acc[0][1][rt][ct]);
    PRIO0();
    // chain 2: read Ah1 (overwrite af) -> q11 (bv=Bh1 held)
#pragma unroll
    for (int rt = 0; rt < 2; ++rt)
#pragma unroll
      for (int ks = 0; ks < 2; ++ks)
        af[rt][ks] = *(const f16x8*)&Ah1[(qwr + rt * 16 + mm) * 64 +
                                         (((ks * 4 + q) ^ mm7)) * 8];
    PRIO1();
#pragma unroll
    for (int rt = 0; rt < 2; ++rt)
#pragma unroll
      for (int ct = 0; ct < 4; ++ct)
#pragma unroll
        for (int ks = 0; ks < 2; ++ks)
          acc[1][1][rt][ct] = mfma_16x16x32(af[rt][ks], bv[ct][ks],
                                            acc[1][1][rt][ct]);
    PRIO0();
    // chain 3: re-read Bh0 (overwrite bv) -> q10 (af=Ah1 held)
#pragma unroll
    for (int ct = 0; ct < 4; ++ct)
#pragma unroll
      for (int ks = 0; ks < 2; ++ks)
        bv[ct][ks] = *(const f16x8*)&Bh0[(qwc + ct * 16 + mm) * 64 +
                                         (((ks * 4 + q) ^ mm7)) * 8];
    PRIO1();
#pragma unroll
    for (int rt = 0; rt < 2; ++rt)
#pragma unroll
      for (int ct = 0; ct < 4; ++ct)
#pragma unroll
        for (int ks = 0; ks < 2; ++ks)
          acc[1][0][rt][ct] = mfma_16x16x32(af[rt][ks], bv[ct][ks],
                                            acc[1][0][rt][ct]);
    PRIO0();
    SCHEDFENCE();
  }
}

// ---- layer 0: h0 = relu(emb . W0T^T + b0), f16 out. 256x256 2-section. ----
__global__ __launch_bounds__(512) void kgemm1(const f16* __restrict__ emb,
                                              const f16* __restrict__ W0T,
                                              const float* __restrict__ small,
                                              f16* __restrict__ h0,
                                              int Nc) {
  __shared__ f16 smem[65536];  // A 64KB | B 64KB; epilogue Cst aliases base
  const int b  = blockIdx.x;
  const int p  = b & 15;
  const int ht = (b >> 4) & 1;
  const int nt = b >> 5;
  const int n0 = nt * 256;
  const int hc0 = ht * 256;
  const int tid = threadIdx.x;
  const int w = tid >> 6;
  const int lane = tid & 63;
  const int q = lane >> 4;
  const int mm = lane & 15;

  const f16* Arow = emb + (size_t)n0 * 512;
  const f16* Brow = W0T + ((size_t)p << 18) + (size_t)hc0 * 512;

  floatx4 acc[2][2][2][4];
#pragma unroll
  for (int i = 0; i < 2; ++i)
#pragma unroll
    for (int j = 0; j < 2; ++j)
#pragma unroll
      for (int k = 0; k < 2; ++k)
#pragma unroll
        for (int l = 0; l < 4; ++l) acc[i][j][k][l] = floatx4{0.f, 0.f, 0.f, 0.f};

  gemm_core(Arow, Brow, smem, acc, w, lane);

  // epilogue: bias+relu+f16, LDS bounce (Cst 64x264), 4 passes of 64 rows
  __syncthreads();
  f16* Cst = smem;
#pragma unroll
  for (int P = 0; P < 4; ++P) {
    if (((w & 3) >> 1) == (P & 1)) {
#pragma unroll
      for (int qn = 0; qn < 2; ++qn)
#pragma unroll
        for (int ct = 0; ct < 4; ++ct) {
          const int col = qn * 128 + (w >> 2) * 64 + ct * 16 + mm;
          const float bvv = small[p * 512 + hc0 + col];
#pragma unroll
          for (int rt = 0; rt < 2; ++rt)
#pragma unroll
            for (int r = 0; r < 4; ++r) {
              float v = acc[P >> 1][qn][rt][ct][r] + bvv;
              v = v > 0.f ? v : 0.f;
              Cst[((w & 1) * 32 + rt * 16 + q * 4 + r) * 264 + col] = (f16)v;
            }
        }
    }
    __syncthreads();
#pragma unroll
    for (int k = 0; k < 4; ++k) {
      const int idx = tid + k * 512;
      const int row = idx >> 5;
      const int ch  = idx & 31;
      uint4 v = *(const uint4*)&Cst[row * 264 + ch * 8];
      *(uint4*)&h0[((size_t)p * Nc + n0 + P * 64 + row) * 512 + hc0 + ch * 8] = v;
    }
    if (P < 3) __syncthreads();
  }
}

// ---- layer 1 GEMM + fused partial layer-2 dot. 256x256 2-section. ----
__global__ __launch_bounds__(512) void kgemm2(const f16* __restrict__ h0,
                                              const f16* __restrict__ W1T,
                                              const float* __restrict__ small,
                                              float* __restrict__ pacc,
                                              int Nc) {
  __shared__ f16 smem[65536];
  __shared__ float oacc[256];
  int p, ht, nt;
  decode_block2(blockIdx.x, gridDim.x, p, ht, nt);
  const int n0 = nt * 256;
  const int hc0 = ht * 256;
  const int tid = threadIdx.x;
  const int w = tid >> 6;
  const int lane = tid & 63;
  const int q = lane >> 4;
  const int mm = lane & 15;
  if (tid < 256) oacc[tid] = 0.f;

  const f16* Arow = h0 + ((size_t)p * Nc + n0) * 512;
  const f16* Brow = W1T + ((size_t)p << 18) + (size_t)hc0 * 512;

  floatx4 acc[2][2][2][4];
#pragma unroll
  for (int i = 0; i < 2; ++i)
#pragma unroll
    for (int j = 0; j < 2; ++j)
#pragma unroll
      for (int k = 0; k < 2; ++k)
#pragma unroll
        for (int l = 0; l < 4; ++l) acc[i][j][k][l] = floatx4{0.f, 0.f, 0.f, 0.f};

  gemm_core(Arow, Brow, smem, acc, w, lane);

  // epilogue: h1 = relu(acc + b1); pd[row] += h1 * W2[col]; reduce over mm
  __syncthreads();
#pragma unroll
  for (int qm = 0; qm < 2; ++qm) {
    float pd[2][4];
#pragma unroll
    for (int rt = 0; rt < 2; ++rt)
#pragma unroll
      for (int r = 0; r < 4; ++r) pd[rt][r] = 0.f;
#pragma unroll
    for (int qn = 0; qn < 2; ++qn)
#pragma unroll
      for (int ct = 0; ct < 4; ++ct) {
        const int col = hc0 + qn * 128 + (w >> 2) * 64 + ct * 16 + mm;
        const float b1v = small[8192 + p * 512 + col];
        const float w2v = small[16384 + p * 512 + col];
#pragma unroll
        for (int rt = 0; rt < 2; ++rt)
#pragma unroll
          for (int r = 0; r < 4; ++r) {
            float v = acc[qm][qn][rt][ct][r] + b1v;
            v = v > 0.f ? v : 0.f;
            pd[rt][r] += v * w2v;
          }
      }
#pragma unroll
    for (int rt = 0; rt < 2; ++rt)
#pragma unroll
      for (int r = 0; r < 4; ++r) {
        float v = pd[rt][r];
        v += __shfl_xor(v, 1, 16);
        v += __shfl_xor(v, 2, 16);
        v += __shfl_xor(v, 4, 16);
        v += __shfl_xor(v, 8, 16);
        if (mm == 0)
          atomicAdd(&oacc[qm * 128 + (w & 3) * 32 + rt * 16 + q * 4 + r], v);
      }
  }
  __syncthreads();
  if (tid < 256)
    pacc[(size_t)(p * 2 + ht) * Nc + n0 + tid] = oacc[tid];
}

// ---- finish: sum 2 ht partials + b2, sigmoid, fp32 out ----
__global__ __launch_bounds__(256) void kfin(const float* __restrict__ pacc,
                                            const float* __restrict__ small,
                                            float* __restrict__ out, int Nc) {
  const int idx = blockIdx.x * 256 + threadIdx.x;
  if (idx >= Nc * 16) return;
  const int n = idx >> 4;
  const int p = idx & 15;
  float v = small[24576 + p];
#pragma unroll
  for (int ht = 0; ht < 2; ++ht) v += pacc[(size_t)(p * 2 + ht) * Nc + n];
  out[(size_t)n * 16 + p] = 1.f / (1.f + expf(-v));
}

// ---- fallback (tiny ws / odd N): slow but correct, fp32 in/out ----
__global__ __launch_bounds__(64) void knaive(const float* __restrict__ emb,
                                             const float* __restrict__ W0,
                                             const float* __restrict__ b0,
                                             const float* __restrict__ W1,
                                             const float* __restrict__ b1,
                                             const float* __restrict__ W2,
                                             const float* __restrict__ b2,
                                             float* __restrict__ out) {
  const int n = blockIdx.x >> 4;
  const int p = blockIdx.x & 15;
  __shared__ float h0s[512];
  __shared__ float h1s[512];
  const size_t wb = (size_t)p << 18;
  const int t = threadIdx.x;
  for (int h = t; h < 512; h += 64) {
    float a = 0.f;
    for (int e = 0; e < 512; ++e)
      a += emb[(size_t)n * 512 + e] * W0[wb + (size_t)e * 512 + h];
    a += b0[p * 512 + h];
    h0s[h] = a > 0.f ? a : 0.f;
  }
  __syncthreads();
  for (int k = t; k < 512; k += 64) {
    float a = 0.f;
    for (int hh = 0; hh < 512; ++hh)
      a += h0s[hh] * W1[wb + (size_t)hh * 512 + k];
    a += b1[p * 512 + k];
    h1s[k] = a > 0.f ? a : 0.f;
  }
  __syncthreads();
  float s = 0.f;
  for (int k = t; k < 512; k += 64) s += h1s[k] * W2[p * 512 + k];
  for (int off = 32; off; off >>= 1) s += __shfl_down(s, off, 64);
  if (t == 0)
    out[(size_t)n * 16 + p] = 1.f / (1.f + expf(-(s + b2[p])));
}

extern "C" void kernel_launch(void* const* d_in, const int* in_sizes, int n_in,
                              void* d_out, int out_size, void* d_ws, size_t ws_size,
                              hipStream_t stream) {
  (void)n_in; (void)out_size;
  const float* emb = (const float*)d_in[0];
  const float* W0  = (const float*)d_in[1];
  const float* b0  = (const float*)d_in[2];
  const float* W1  = (const float*)d_in[3];
  const float* b1  = (const float*)d_in[4];
  const float* W2  = (const float*)d_in[5];
  const float* b2  = (const float*)d_in[6];
  float* out = (float*)d_out;

  const int N = in_sizes[0] / 512;

  char* ws = (char*)d_ws;
  f16*   W0T    = (f16*)ws;                                  // 8 MB
  f16*   W1T    = (f16*)(ws + (8ll << 20));                  // 8 MB
  float* smallF = (float*)(ws + (16ll << 20));               // 128 KB
  float* pacc   = (float*)(ws + (16ll << 20) + 131072);      // <=256*N B slot
  f16*   embB   = (f16*)(ws + (16ll << 20) + 131072 + (size_t)N * 256);
  f16*   h0     = (f16*)(ws + (16ll << 20) + 131072 + (size_t)N * 256 +
                         (size_t)N * 1024);
  const long long fixed = (16ll << 20) + 131072 + (long long)N * 256 +
                          (long long)N * 1024;
  long long avail = (long long)ws_size - fixed;
  long long rows = avail > 0 ? avail / (16 * 512 * 2) : 0;
  int Nc = (int)((rows / 256) * 256);
  if (Nc > N) Nc = N;

  if (Nc < 256 || (N % 256) != 0) {
    knaive<<<dim3(N * PDIM), dim3(64), 0, stream>>>(emb, W0, b0, W1, b1, W2,
                                                    b2, out);
    return;
  }

  const int n8 = N * 512 / 8;
  const int nConvBlk = (n8 + 255) / 256;
  kprep<<<dim3(256 + nConvBlk + 97), dim3(256), 0, stream>>>(
      emb, W0, W1, b0, b1, W2, b2, embB, W0T, W1T, smallF, n8, nConvBlk);

  for (int noff = 0; noff < N; noff += Nc) {
    const int cur = (N - noff < Nc) ? (N - noff) : Nc;
    kgemm1<<<dim3(32 * (cur / 256)), dim3(512), 0, stream>>>(
        embB + (size_t)noff * 512, W0T, smallF, h0, cur);
    kgemm2<<<dim3(32 * (cur / 256)), dim3(512), 0, stream>>>(
        h0, W1T, smallF, pacc, cur);
    kfin<<<dim3((cur * 16 + 255) / 256), dim3(256), 0, stream>>>(
        pacc, smallF, out + (size_t)noff * 16, cur);
  }
}

// Round 12
// 238.144 us; speedup vs baseline: 1.1877x; 1.0016x over previous
//
#include <hip/hip_runtime.h>
#include <stdint.h>

typedef _Float16 f16;
typedef _Float16 f16x8 __attribute__((ext_vector_type(8)));
typedef float floatx4 __attribute__((ext_vector_type(4)));
typedef unsigned short u16;

#define PDIM 16

__device__ __forceinline__ floatx4 mfma_16x16x32(f16x8 a, f16x8 b, floatx4 c) {
  return __builtin_amdgcn_mfma_f32_16x16x32_f16(a, b, c, 0, 0, 0);
}

// async 16B/lane global->LDS; LDS dst = wave-uniform base + lane*16.
__device__ __forceinline__ void stage16(const f16* g, f16* lds_base) {
  __builtin_amdgcn_global_load_lds(
      (const __attribute__((address_space(1))) void*)g,
      (__attribute__((address_space(3))) void*)lds_base, 16, 0, 0);
}

#define WAITVM4() asm volatile("s_waitcnt vmcnt(4)" ::: "memory")
#define WAITVM2() asm volatile("s_waitcnt vmcnt(2)" ::: "memory")
#define WAITVM0() asm volatile("s_waitcnt vmcnt(0)" ::: "memory")
#define BAR()     asm volatile("s_barrier" ::: "memory")
#define LGKM0()   asm volatile("s_waitcnt lgkmcnt(0)" ::: "memory")
#define SCHEDFENCE() __builtin_amdgcn_sched_barrier(0)
#define PRIO1() __builtin_amdgcn_s_setprio(1)
#define PRIO0() __builtin_amdgcn_s_setprio(0)

// ================= dual-core 256x256 GEMM (R12 best-of-both) ================
// A/B outcome (R9-R11): kgemm1 prefers the 4-PHASE schedule (93us verified
// twice; 2-section = 105us). kgemm2 (A=h0 from L3/HBM, higher latency
// variance) improved under the 2-SECTION schedule (fewer barrier convoys).
// Both cores use identical LDS addressing + per-acc K order -> bit-identical
// outputs. kgemm1 -> core4, kgemm2 -> core2.
// ===========================================================================

// XCD-affinity decode for kgemm2 (A = h0[p] is per-p; measured win).
__device__ __forceinline__ void decode_block2(int b, int nwg, int& p, int& ht,
                                              int& nt) {
  const int NT = nwg >> 5;  // number of 256-row n-tiles
  if ((NT & 7) == 0) {
    const int x  = b & 7;
    const int u  = b >> 3;
    const int i  = u & 31;     // 8 ntl x 2 pl x 2 ht
    const int cg = u >> 5;
    ht = i & 1;
    const int pl  = (i >> 1) & 1;
    const int ntl = i >> 2;
    p  = x * 2 + pl;
    nt = cg * 8 + ntl;
  } else {
    p  = b & 15;
    ht = (b >> 4) & 1;
    nt = b >> 5;
  }
}

// ---- fused prep ----
// [0,256): W0/W1 transpose via XOR-swizzled LDS panel, both sides coalesced.
// [256,256+nConvBlk): emb fp32->f16. Then biases+W2 pack (fp32).
__global__ __launch_bounds__(256) void kprep(const float* __restrict__ emb,
                                             const float* __restrict__ W0,
                                             const float* __restrict__ W1,
                                             const float* __restrict__ b0,
                                             const float* __restrict__ b1,
                                             const float* __restrict__ W2,
                                             const float* __restrict__ b2,
                                             f16* __restrict__ embB,
                                             f16* __restrict__ W0T,
                                             f16* __restrict__ W1T,
                                             float* __restrict__ smallF,
                                             int n8, int nConvBlk) {
  __shared__ unsigned int tile[16384];  // 512 rows x 32 h-pair words = 64 KB
  const int b = blockIdx.x;
  const int t = threadIdx.x;
  if (b < 256) {
    const int m  = b >> 7;         // 0: W0, 1: W1
    const int p  = (b >> 3) & 15;
    const int tc = b & 7;          // h-tile (64 h)
    const int hb = tc * 64;
    const float* src = (m ? W1 : W0) + ((size_t)p << 18);
    f16*         dst = (m ? W1T : W0T) + ((size_t)p << 18);
    const int er = t >> 2;         // base e-row 0..63
    const int hq = t & 3;
#pragma unroll
    for (int j = 0; j < 8; ++j) {
      const int e   = er + j * 64;
      const int swz = (e >> 3) & 31;
      const float* rp = src + (size_t)e * 512 + hb;
#pragma unroll
      for (int i = 0; i < 4; ++i) {
        const int hc = hq * 4 + i * 16;   // lanes 0-3 cover 64B contiguous
        float4 v = *(const float4*)(rp + hc);
        union { f16 h2[2]; unsigned int u; } w0, w1;
        w0.h2[0] = (f16)v.x; w0.h2[1] = (f16)v.y;
        w1.h2[0] = (f16)v.z; w1.h2[1] = (f16)v.w;
        const int hp = hc >> 1;           // even
        tile[e * 32 + (hp ^ swz)]       = w0.u;
        tile[e * 32 + ((hp + 1) ^ swz)] = w1.u;
      }
    }
    __syncthreads();
    const int w = t >> 6, l = t & 63;
#pragma unroll
    for (int P = 0; P < 16; ++P) {
      const int hl  = P * 4 + w;
      const int hp  = hl >> 1;
      const int sub = hl & 1;
      union { u16 uu[8]; uint4 v; } o;
#pragma unroll
      for (int j = 0; j < 8; ++j) {
        const int e = l * 8 + j;
        const unsigned int word = tile[e * 32 + (hp ^ ((e >> 3) & 31))];
        o.uu[j] = (u16)(sub ? (word >> 16) : (word & 0xffffu));
      }
      *(uint4*)(dst + (size_t)(hb + hl) * 512 + l * 8) = o.v;
    }
  } else if (b < 256 + nConvBlk) {
    const int i = (b - 256) * 256 + t;
    if (i < n8) {
      const float4* s = (const float4*)emb;
      float4 a = s[i * 2], bb = s[i * 2 + 1];
      union { f16 h[8]; uint4 v; } o;
      o.h[0] = (f16)a.x;  o.h[1] = (f16)a.y;  o.h[2] = (f16)a.z;  o.h[3] = (f16)a.w;
      o.h[4] = (f16)bb.x; o.h[5] = (f16)bb.y; o.h[6] = (f16)bb.z; o.h[7] = (f16)bb.w;
      *(uint4*)(embB + (size_t)i * 8) = o.v;
    }
  } else {
    const int j = (b - 256 - nConvBlk) * 256 + t;
    if (j < 24592) {
      const float* src;
      int off;
      if (j < 8192)       { src = b0; off = j; }
      else if (j < 16384) { src = b1; off = j - 8192; }
      else if (j < 24576) { src = W2; off = j - 16384; }
      else                { src = b2; off = j - 24576; }
      smallF[j] = src[off];
    }
  }
}

// stage one (matrix, half) unit: 16 KB, 2 loads per thread, fixed order.
__device__ __forceinline__ void stageU(const f16* M, int h, int tt, f16* buf,
                                       int w, int srow8, int kg8) {
  stage16(M + (size_t)(h * 128 + w * 8 + srow8) * 512 + tt * 64 + kg8,
          buf + (w * 8) * 64);
  stage16(M + (size_t)(h * 128 + 64 + w * 8 + srow8) * 512 + tt * 64 + kg8,
          buf + (64 + w * 8) * 64);
}

// ---------------- core4: 4-phase/K-tile (R9; kgemm1's best) ----------------
__device__ __forceinline__ void gemm_core4(const f16* __restrict__ Arow,
                                           const f16* __restrict__ Brow,
                                           f16* smem, floatx4 (*acc)[2][2][4],
                                           int w, int lane) {
  const int q   = lane >> 4;
  const int mm  = lane & 15;
  const int mm7 = mm & 7;
  const int qwr = (w & 3) * 32;
  const int qwc = (w >> 2) * 64;
  const int srow8 = lane >> 3;
  const int kg8   = (((lane & 7) ^ ((lane >> 3) & 7)) * 8);

  stageU(Arow, 0, 0, smem + 0 * 8192, w, srow8, kg8);
  stageU(Brow, 0, 0, smem + 32768 + 0 * 8192, w, srow8, kg8);
  stageU(Brow, 1, 0, smem + 32768 + 1 * 8192, w, srow8, kg8);
  stageU(Arow, 1, 0, smem + 1 * 8192, w, srow8, kg8);

  f16x8 af[2][2], bv[4][2];

  for (int t = 0; t < 8; ++t) {
    const int cb = t & 1;
    const f16* Ah0 = smem + (cb * 2 + 0) * 8192;
    const f16* Ah1 = smem + (cb * 2 + 1) * 8192;
    const f16* Bh0 = smem + 32768 + (cb * 2 + 0) * 8192;
    const f16* Bh1 = smem + 32768 + (cb * 2 + 1) * 8192;
    const int nb = cb ^ 1;
    f16* nAh0 = smem + (nb * 2 + 0) * 8192;
    f16* nAh1 = smem + (nb * 2 + 1) * 8192;
    f16* nBh0 = smem + 32768 + (nb * 2 + 0) * 8192;
    f16* nBh1 = smem + 32768 + (nb * 2 + 1) * 8192;

    // ---- phase 0: quadrant (0,0) ----
    WAITVM4();
    BAR();
#pragma unroll
    for (int rt = 0; rt < 2; ++rt)
#pragma unroll
      for (int ks = 0; ks < 2; ++ks)
        af[rt][ks] = *(const f16x8*)&Ah0[(qwr + rt * 16 + mm) * 64 +
                                         (((ks * 4 + q) ^ mm7)) * 8];
#pragma unroll
    for (int ct = 0; ct < 4; ++ct)
#pragma unroll
      for (int ks = 0; ks < 2; ++ks)
        bv[ct][ks] = *(const f16x8*)&Bh0[(qwc + ct * 16 + mm) * 64 +
                                         (((ks * 4 + q) ^ mm7)) * 8];
    if (t < 7) stageU(Arow, 0, t + 1, nAh0, w, srow8, kg8);
    LGKM0();
    PRIO1();
#pragma unroll
    for (int rt = 0; rt < 2; ++rt)
#pragma unroll
      for (int ct = 0; ct < 4; ++ct)
#pragma unroll
        for (int ks = 0; ks < 2; ++ks)
          acc[0][0][rt][ct] = mfma_16x16x32(af[rt][ks], bv[ct][ks],
                                            acc[0][0][rt][ct]);
    PRIO0();
    SCHEDFENCE();

    // ---- phase 1: quadrant (0,1) — af held, read B half 1 ----
    if (t < 7) { WAITVM4(); } else { WAITVM2(); }
    BAR();
#pragma unroll
    for (int ct = 0; ct < 4; ++ct)
#pragma unroll
      for (int ks = 0; ks < 2; ++ks)
        bv[ct][ks] = *(const f16x8*)&Bh1[(qwc + ct * 16 + mm) * 64 +
                                         (((ks * 4 + q) ^ mm7)) * 8];
    if (t < 7) stageU(Brow, 0, t + 1, nBh0, w, srow8, kg8);
    LGKM0();
    PRIO1();
#pragma unroll
    for (int rt = 0; rt < 2; ++rt)
#pragma unroll
      for (int ct = 0; ct < 4; ++ct)
#pragma unroll
        for (int ks = 0; ks < 2; ++ks)
          acc[0][1][rt][ct] = mfma_16x16x32(af[rt][ks], bv[ct][ks],
                                            acc[0][1][rt][ct]);
    PRIO0();
    SCHEDFENCE();

    // ---- phase 2: quadrant (1,1) — bv held, read A half 1 ----
    if (t < 7) { WAITVM4(); } else { WAITVM0(); }
    BAR();
#pragma unroll
    for (int rt = 0; rt < 2; ++rt)
#pragma unroll
      for (int ks = 0; ks < 2; ++ks)
        af[rt][ks] = *(const f16x8*)&Ah1[(qwr + rt * 16 + mm) * 64 +
                                         (((ks * 4 + q) ^ mm7)) * 8];
    if (t < 7) stageU(Brow, 1, t + 1, nBh1, w, srow8, kg8);
    LGKM0();
    PRIO1();
#pragma unroll
    for (int rt = 0; rt < 2; ++rt)
#pragma unroll
      for (int ct = 0; ct < 4; ++ct)
#pragma unroll
        for (int ks = 0; ks < 2; ++ks)
          acc[1][1][rt][ct] = mfma_16x16x32(af[rt][ks], bv[ct][ks],
                                            acc[1][1][rt][ct]);
    PRIO0();
    SCHEDFENCE();

    // ---- phase 3: quadrant (1,0) — af held, re-read B half 0 ----
    BAR();
#pragma unroll
    for (int ct = 0; ct < 4; ++ct)
#pragma unroll
      for (int ks = 0; ks < 2; ++ks)
        bv[ct][ks] = *(const f16x8*)&Bh0[(qwc + ct * 16 + mm) * 64 +
                                         (((ks * 4 + q) ^ mm7)) * 8];
    if (t < 7) stageU(Arow, 1, t + 1, nAh1, w, srow8, kg8);
    LGKM0();
    PRIO1();
#pragma unroll
    for (int rt = 0; rt < 2; ++rt)
#pragma unroll
      for (int ct = 0; ct < 4; ++ct)
#pragma unroll
        for (int ks = 0; ks < 2; ++ks)
          acc[1][0][rt][ct] = mfma_16x16x32(af[rt][ks], bv[ct][ks],
                                            acc[1][0][rt][ct]);
    PRIO0();
    SCHEDFENCE();
  }
}

// ---------------- core2: 2-section/K-tile (R11; kgemm2's best) --------------
__device__ __forceinline__ void gemm_core2(const f16* __restrict__ Arow,
                                           const f16* __restrict__ Brow,
                                           f16* smem, floatx4 (*acc)[2][2][4],
                                           int w, int lane) {
  const int q   = lane >> 4;
  const int mm  = lane & 15;
  const int mm7 = mm & 7;
  const int qwr = (w & 3) * 32;
  const int qwc = (w >> 2) * 64;
  const int srow8 = lane >> 3;
  const int kg8   = (((lane & 7) ^ ((lane >> 3) & 7)) * 8);

  stageU(Arow, 0, 0, smem + 0 * 8192, w, srow8, kg8);
  stageU(Brow, 0, 0, smem + 32768 + 0 * 8192, w, srow8, kg8);
  stageU(Brow, 1, 0, smem + 32768 + 1 * 8192, w, srow8, kg8);
  stageU(Arow, 1, 0, smem + 1 * 8192, w, srow8, kg8);

  f16x8 af[2][2], bv[4][2];

  for (int t = 0; t < 8; ++t) {
    const int cb = t & 1;
    const f16* Ah0 = smem + (cb * 2 + 0) * 8192;
    const f16* Ah1 = smem + (cb * 2 + 1) * 8192;
    const f16* Bh0 = smem + 32768 + (cb * 2 + 0) * 8192;
    const f16* Bh1 = smem + 32768 + (cb * 2 + 1) * 8192;
    const int nb = cb ^ 1;
    f16* nAh0 = smem + (nb * 2 + 0) * 8192;
    f16* nAh1 = smem + (nb * 2 + 1) * 8192;
    f16* nBh0 = smem + 32768 + (nb * 2 + 0) * 8192;
    f16* nBh1 = smem + 32768 + (nb * 2 + 1) * 8192;

    // ======== section 1: needs A0,B0 of t (oldest 4 loads) ========
    WAITVM4();
    SCHEDFENCE();
    BAR();
#pragma unroll
    for (int rt = 0; rt < 2; ++rt)
#pragma unroll
      for (int ks = 0; ks < 2; ++ks)
        af[rt][ks] = *(const f16x8*)&Ah0[(qwr + rt * 16 + mm) * 64 +
                                         (((ks * 4 + q) ^ mm7)) * 8];
#pragma unroll
    for (int ct = 0; ct < 4; ++ct)
#pragma unroll
      for (int ks = 0; ks < 2; ++ks)
        bv[ct][ks] = *(const f16x8*)&Bh0[(qwc + ct * 16 + mm) * 64 +
                                         (((ks * 4 + q) ^ mm7)) * 8];
    if (t < 7) {
      stageU(Arow, 0, t + 1, nAh0, w, srow8, kg8);
      stageU(Brow, 0, t + 1, nBh0, w, srow8, kg8);
    }
    PRIO1();
#pragma unroll
    for (int rt = 0; rt < 2; ++rt)
#pragma unroll
      for (int ct = 0; ct < 4; ++ct)
#pragma unroll
        for (int ks = 0; ks < 2; ++ks)
          acc[0][0][rt][ct] = mfma_16x16x32(af[rt][ks], bv[ct][ks],
                                            acc[0][0][rt][ct]);
    PRIO0();

    // ======== section 2: needs B1,A1 of t (next-oldest 4 loads) ========
    if (t < 7) { WAITVM4(); } else { WAITVM0(); }
    SCHEDFENCE();
    BAR();
#pragma unroll
    for (int ct = 0; ct < 4; ++ct)
#pragma unroll
      for (int ks = 0; ks < 2; ++ks)
        bv[ct][ks] = *(const f16x8*)&Bh1[(qwc + ct * 16 + mm) * 64 +
                                         (((ks * 4 + q) ^ mm7)) * 8];
    if (t < 7) {
      stageU(Brow, 1, t + 1, nBh1, w, srow8, kg8);
      stageU(Arow, 1, t + 1, nAh1, w, srow8, kg8);
    }
    PRIO1();
#pragma unroll
    for (int rt = 0; rt < 2; ++rt)
#pragma unroll
      for (int ct = 0; ct < 4; ++ct)
#pragma unroll
        for (int ks = 0; ks < 2; ++ks)
          acc[0][1][rt][ct] = mfma_16x16x32(af[rt][ks], bv[ct][ks],
                                            acc[0][1][rt][ct]);
    PRIO0();
#pragma unroll
    for (int rt = 0; rt < 2; ++rt)
#pragma unroll
      for (int ks = 0; ks < 2; ++ks)
        af[rt][ks] = *(const f16x8*)&Ah1[(qwr + rt * 16 + mm) * 64 +
                                         (((ks * 4 + q) ^ mm7)) * 8];
    PRIO1();
#pragma unroll
    for (int rt = 0; rt < 2; ++rt)
#pragma unroll
      for (int ct = 0; ct < 4; ++ct)
#pragma unroll
        for (int ks = 0; ks < 2; ++ks)
          acc[1][1][rt][ct] = mfma_16x16x32(af[rt][ks], bv[ct][ks],
                                            acc[1][1][rt][ct]);
    PRIO0();
#pragma unroll
    for (int ct = 0; ct < 4; ++ct)
#pragma unroll
      for (int ks = 0; ks < 2; ++ks)
        bv[ct][ks] = *(const f16x8*)&Bh0[(qwc + ct * 16 + mm) * 64 +
                                         (((ks * 4 + q) ^ mm7)) * 8];
    PRIO1();
#pragma unroll
    for (int rt = 0; rt < 2; ++rt)
#pragma unroll
      for (int ct = 0; ct < 4; ++ct)
#pragma unroll
        for (int ks = 0; ks < 2; ++ks)
          acc[1][0][rt][ct] = mfma_16x16x32(af[rt][ks], bv[ct][ks],
                                            acc[1][0][rt][ct]);
    PRIO0();
    SCHEDFENCE();
  }
}

// ---- layer 0: h0 = relu(emb . W0T^T + b0), f16 out. 256x256, core4. ----
__global__ __launch_bounds__(512) void kgemm1(const f16* __restrict__ emb,
                                              const f16* __restrict__ W0T,
                                              const float* __restrict__ small,
                                              f16* __restrict__ h0,
                                              int Nc) {
  __shared__ f16 smem[65536];  // A 64KB | B 64KB; epilogue Cst aliases base
  const int b  = blockIdx.x;
  const int p  = b & 15;
  const int ht = (b >> 4) & 1;
  const int nt = b >> 5;
  const int n0 = nt * 256;
  const int hc0 = ht * 256;
  const int tid = threadIdx.x;
  const int w = tid >> 6;
  const int lane = tid & 63;
  const int q = lane >> 4;
  const int mm = lane & 15;

  const f16* Arow = emb + (size_t)n0 * 512;
  const f16* Brow = W0T + ((size_t)p << 18) + (size_t)hc0 * 512;

  floatx4 acc[2][2][2][4];
#pragma unroll
  for (int i = 0; i < 2; ++i)
#pragma unroll
    for (int j = 0; j < 2; ++j)
#pragma unroll
      for (int k = 0; k < 2; ++k)
#pragma unroll
        for (int l = 0; l < 4; ++l) acc[i][j][k][l] = floatx4{0.f, 0.f, 0.f, 0.f};

  gemm_core4(Arow, Brow, smem, acc, w, lane);

  // epilogue: bias+relu+f16, LDS bounce (Cst 64x264), 4 passes of 64 rows
  __syncthreads();
  f16* Cst = smem;
#pragma unroll
  for (int P = 0; P < 4; ++P) {
    if (((w & 3) >> 1) == (P & 1)) {
#pragma unroll
      for (int qn = 0; qn < 2; ++qn)
#pragma unroll
        for (int ct = 0; ct < 4; ++ct) {
          const int col = qn * 128 + (w >> 2) * 64 + ct * 16 + mm;
          const float bvv = small[p * 512 + hc0 + col];
#pragma unroll
          for (int rt = 0; rt < 2; ++rt)
#pragma unroll
            for (int r = 0; r < 4; ++r) {
              float v = acc[P >> 1][qn][rt][ct][r] + bvv;
              v = v > 0.f ? v : 0.f;
              Cst[((w & 1) * 32 + rt * 16 + q * 4 + r) * 264 + col] = (f16)v;
            }
        }
    }
    __syncthreads();
#pragma unroll
    for (int k = 0; k < 4; ++k) {
      const int idx = tid + k * 512;
      const int row = idx >> 5;
      const int ch  = idx & 31;
      uint4 v = *(const uint4*)&Cst[row * 264 + ch * 8];
      *(uint4*)&h0[((size_t)p * Nc + n0 + P * 64 + row) * 512 + hc0 + ch * 8] = v;
    }
    if (P < 3) __syncthreads();
  }
}

// ---- layer 1 GEMM + fused partial layer-2 dot. 256x256, core2. ----
__global__ __launch_bounds__(512) void kgemm2(const f16* __restrict__ h0,
                                              const f16* __restrict__ W1T,
                                              const float* __restrict__ small,
                                              float* __restrict__ pacc,
                                              int Nc) {
  __shared__ f16 smem[65536];
  __shared__ float oacc[256];
  int p, ht, nt;
  decode_block2(blockIdx.x, gridDim.x, p, ht, nt);
  const int n0 = nt * 256;
  const int hc0 = ht * 256;
  const int tid = threadIdx.x;
  const int w = tid >> 6;
  const int lane = tid & 63;
  const int q = lane >> 4;
  const int mm = lane & 15;
  if (tid < 256) oacc[tid] = 0.f;

  const f16* Arow = h0 + ((size_t)p * Nc + n0) * 512;
  const f16* Brow = W1T + ((size_t)p << 18) + (size_t)hc0 * 512;

  floatx4 acc[2][2][2][4];
#pragma unroll
  for (int i = 0; i < 2; ++i)
#pragma unroll
    for (int j = 0; j < 2; ++j)
#pragma unroll
      for (int k = 0; k < 2; ++k)
#pragma unroll
        for (int l = 0; l < 4; ++l) acc[i][j][k][l] = floatx4{0.f, 0.f, 0.f, 0.f};

  gemm_core2(Arow, Brow, smem, acc, w, lane);

  // epilogue: h1 = relu(acc + b1); pd[row] += h1 * W2[col]; reduce over mm
  __syncthreads();
#pragma unroll
  for (int qm = 0; qm < 2; ++qm) {
    float pd[2][4];
#pragma unroll
    for (int rt = 0; rt < 2; ++rt)
#pragma unroll
      for (int r = 0; r < 4; ++r) pd[rt][r] = 0.f;
#pragma unroll
    for (int qn = 0; qn < 2; ++qn)
#pragma unroll
      for (int ct = 0; ct < 4; ++ct) {
        const int col = hc0 + qn * 128 + (w >> 2) * 64 + ct * 16 + mm;
        const float b1v = small[8192 + p * 512 + col];
        const float w2v = small[16384 + p * 512 + col];
#pragma unroll
        for (int rt = 0; rt < 2; ++rt)
#pragma unroll
          for (int r = 0; r < 4; ++r) {
            float v = acc[qm][qn][rt][ct][r] + b1v;
            v = v > 0.f ? v : 0.f;
            pd[rt][r] += v * w2v;
          }
      }
#pragma unroll
    for (int rt = 0; rt < 2; ++rt)
#pragma unroll
      for (int r = 0; r < 4; ++r) {
        float v = pd[rt][r];
        v += __shfl_xor(v, 1, 16);
        v += __shfl_xor(v, 2, 16);
        v += __shfl_xor(v, 4, 16);
        v += __shfl_xor(v, 8, 16);
        if (mm == 0)
          atomicAdd(&oacc[qm * 128 + (w & 3) * 32 + rt * 16 + q * 4 + r], v);
      }
  }
  __syncthreads();
  if (tid < 256)
    pacc[(size_t)(p * 2 + ht) * Nc + n0 + tid] = oacc[tid];
}

// ---- finish: sum 2 ht partials + b2, sigmoid, fp32 out ----
__global__ __launch_bounds__(256) void kfin(const float* __restrict__ pacc,
                                            const float* __restrict__ small,
                                            float* __restrict__ out, int Nc) {
  const int idx = blockIdx.x * 256 + threadIdx.x;
  if (idx >= Nc * 16) return;
  const int n = idx >> 4;
  const int p = idx & 15;
  float v = small[24576 + p];
#pragma unroll
  for (int ht = 0; ht < 2; ++ht) v += pacc[(size_t)(p * 2 + ht) * Nc + n];
  out[(size_t)n * 16 + p] = 1.f / (1.f + expf(-v));
}

// ---- fallback (tiny ws / odd N): slow but correct, fp32 in/out ----
__global__ __launch_bounds__(64) void knaive(const float* __restrict__ emb,
                                             const float* __restrict__ W0,
                                             const float* __restrict__ b0,
                                             const float* __restrict__ W1,
                                             const float* __restrict__ b1,
                                             const float* __restrict__ W2,
                                             const float* __restrict__ b2,
                                             float* __restrict__ out) {
  const int n = blockIdx.x >> 4;
  const int p = blockIdx.x & 15;
  __shared__ float h0s[512];
  __shared__ float h1s[512];
  const size_t wb = (size_t)p << 18;
  const int t = threadIdx.x;
  for (int h = t; h < 512; h += 64) {
    float a = 0.f;
    for (int e = 0; e < 512; ++e)
      a += emb[(size_t)n * 512 + e] * W0[wb + (size_t)e * 512 + h];
    a += b0[p * 512 + h];
    h0s[h] = a > 0.f ? a : 0.f;
  }
  __syncthreads();
  for (int k = t; k < 512; k += 64) {
    float a = 0.f;
    for (int hh = 0; hh < 512; ++hh)
      a += h0s[hh] * W1[wb + (size_t)hh * 512 + k];
    a += b1[p * 512 + k];
    h1s[k] = a > 0.f ? a : 0.f;
  }
  __syncthreads();
  float s = 0.f;
  for (int k = t; k < 512; k += 64) s += h1s[k] * W2[p * 512 + k];
  for (int off = 32; off; off >>= 1) s += __shfl_down(s, off, 64);
  if (t == 0)
    out[(size_t)n * 16 + p] = 1.f / (1.f + expf(-(s + b2[p])));
}

extern "C" void kernel_launch(void* const* d_in, const int* in_sizes, int n_in,
                              void* d_out, int out_size, void* d_ws, size_t ws_size,
                              hipStream_t stream) {
  (void)n_in; (void)out_size;
  const float* emb = (const float*)d_in[0];
  const float* W0  = (const float*)d_in[1];
  const float* b0  = (const float*)d_in[2];
  const float* W1  = (const float*)d_in[3];
  const float* b1  = (const float*)d_in[4];
  const float* W2  = (const float*)d_in[5];
  const float* b2  = (const float*)d_in[6];
  float* out = (float*)d_out;

  const int N = in_sizes[0] / 512;

  char* ws = (char*)d_ws;
  f16*   W0T    = (f16*)ws;                                  // 8 MB
  f16*   W1T    = (f16*)(ws + (8ll << 20));                  // 8 MB
  float* smallF = (float*)(ws + (16ll << 20));               // 128 KB
  float* pacc   = (float*)(ws + (16ll << 20) + 131072);      // <=256*N B slot
  f16*   embB   = (f16*)(ws + (16ll << 20) + 131072 + (size_t)N * 256);
  f16*   h0     = (f16*)(ws + (16ll << 20) + 131072 + (size_t)N * 256 +
                         (size_t)N * 1024);
  const long long fixed = (16ll << 20) + 131072 + (long long)N * 256 +
                          (long long)N * 1024;
  long long avail = (long long)ws_size - fixed;
  long long rows = avail > 0 ? avail / (16 * 512 * 2) : 0;
  int Nc = (int)((rows / 256) * 256);
  if (Nc > N) Nc = N;

  if (Nc < 256 || (N % 256) != 0) {
    knaive<<<dim3(N * PDIM), dim3(64), 0, stream>>>(emb, W0, b0, W1, b1, W2,
                                                    b2, out);
    return;
  }

  const int n8 = N * 512 / 8;
  const int nConvBlk = (n8 + 255) / 256;
  kprep<<<dim3(256 + nConvBlk + 97), dim3(256), 0, stream>>>(
      emb, W0, W1, b0, b1, W2, b2, embB, W0T, W1T, smallF, n8, nConvBlk);

  for (int noff = 0; noff < N; noff += Nc) {
    const int cur = (N - noff < Nc) ? (N - noff) : Nc;
    kgemm1<<<dim3(32 * (cur / 256)), dim3(512), 0, stream>>>(
        embB + (size_t)noff * 512, W0T, smallF, h0, cur);
    kgemm2<<<dim3(32 * (cur / 256)), dim3(512), 0, stream>>>(
        h0, W1T, smallF, pacc, cur);
    kfin<<<dim3((cur * 16 + 255) / 256), dim3(256), 0, stream>>>(
        pacc, smallF, out + (size_t)noff * 16, cur);
  }
}